// Round 1
// baseline (1060.897 us; speedup 1.0000x reference)
//
#include <hip/hip_runtime.h>
#include <cmath>

// AdaAttnNoConv: b=4, C=512, hw=4096 (fp32 in/out).
// out[b][v][q] = S[q][v] * IN(c_x)[b][v][q] + M[q][v]
//   A = softmax_k( IN(c_1x)^T[q][c] . IN(s_1x)[c][k] )
//   M = A V, Var = A V^2 - M^2, S = sqrt(clip(Var,1e-6)), V[k][v] = s_x[b][v][k]
//
// Strategy: f16 MFMA (16x16x32) everywhere; exact 2-pass softmax (stats pass,
// then fused recompute+PV pass with 2-way channel split). No S/P matrix
// materialized. ws usage ~50.6 MB (Qt/Kt/Vh f16 + stats + m/l partials).

#define B_  4
#define C_  512
#define HW_ 4096

typedef _Float16 f16;
typedef _Float16 f16x8 __attribute__((ext_vector_type(8)));
typedef _Float16 f16x4 __attribute__((ext_vector_type(4)));
typedef float    f32x4 __attribute__((ext_vector_type(4)));

// Verified gfx950 fragment layouts (learn_hip m89/m91/m120):
//  A[m][k]: m = lane&15, k = (lane>>4)*8 + j   (8 contiguous k per lane)
//  B[k][n]: n = lane&15, k = (lane>>4)*8 + j
//  C/D[m][n]: n = lane&15, m = (lane>>4)*4 + reg
__device__ __forceinline__ f32x4 mfma16(f16x8 a, f16x8 b, f32x4 c) {
  return __builtin_amdgcn_mfma_f32_16x16x32_f16(a, b, c, 0, 0, 0);
}

// async global->LDS, 16B/lane. lds dest is wave-uniform base + lane*16.
__device__ __forceinline__ void g2l16(const f16* g, f16* l) {
  __builtin_amdgcn_global_load_lds(
      (const __attribute__((address_space(1))) void*)g,
      (__attribute__((address_space(3))) void*)l, 16, 0, 0);
}

// ---------------- pass 0: instance-norm stats (mean, rstd) ----------------
__global__ __launch_bounds__(256) void k_stats(
    const float* __restrict__ cx, const float* __restrict__ c1,
    const float* __restrict__ s1,
    float2* __restrict__ cxs, float2* __restrict__ c1s, float2* __restrict__ s1s) {
  int c = blockIdx.x, b = blockIdx.y, t = blockIdx.z;
  const float* src = (t == 0 ? cx : (t == 1 ? c1 : s1)) + (size_t)(b * C_ + c) * HW_;
  float s = 0.f, q = 0.f;
  const float4* src4 = (const float4*)src;
  for (int i = threadIdx.x; i < HW_ / 4; i += 256) {
    float4 v = src4[i];
    s += v.x + v.y + v.z + v.w;
    q += v.x * v.x + v.y * v.y + v.z * v.z + v.w * v.w;
  }
#pragma unroll
  for (int off = 1; off < 64; off <<= 1) {
    s += __shfl_xor(s, off);
    q += __shfl_xor(q, off);
  }
  __shared__ float ss[4], sq[4];
  int wv = threadIdx.x >> 6;
  if ((threadIdx.x & 63) == 0) { ss[wv] = s; sq[wv] = q; }
  __syncthreads();
  if (threadIdx.x == 0) {
    float S = ss[0] + ss[1] + ss[2] + ss[3];
    float Q = sq[0] + sq[1] + sq[2] + sq[3];
    float mean = S * (1.f / HW_);
    float var = Q * (1.f / HW_) - mean * mean;
    float2 r;
    r.x = mean;
    r.y = rsqrtf(var + 1e-5f);
    (t == 0 ? cxs : (t == 1 ? c1s : s1s))[b * C_ + c] = r;
  }
}

// ------- pass 1: normalize + transpose (b,c,p) f32 -> (b,p,c) f16 ---------
__global__ __launch_bounds__(256) void k_prept(
    const float* __restrict__ src, const float2* __restrict__ st,
    f16* __restrict__ dst) {
  int pb = blockIdx.x * 64, cb = blockIdx.y * 64, b = blockIdx.z;
  __shared__ float t[64][65];
  int tj = threadIdx.x & 63, tr = threadIdx.x >> 6;
#pragma unroll 4
  for (int p = 0; p < 16; ++p) {
    int cl = p * 4 + tr;
    float2 mr = st[b * C_ + cb + cl];
    float v = src[(size_t)(b * C_ + cb + cl) * HW_ + pb + tj];
    t[cl][tj] = (v - mr.x) * mr.y;
  }
  __syncthreads();
#pragma unroll 4
  for (int p = 0; p < 16; ++p) {
    int pr = p * 4 + tr;
    dst[(size_t)(b * HW_ + pb + pr) * C_ + cb + tj] = (f16)t[tj][pr];
  }
}

// ---------------- pass 1b: V = s_x -> f16 (same layout) -------------------
__global__ __launch_bounds__(256) void k_prepv(const float* __restrict__ src,
                                               f16* __restrict__ dst) {
  int i = blockIdx.x * 256 + threadIdx.x;  // over B_*C_*HW_/4 float4s
  float4 v = ((const float4*)src)[i];
  f16x4 o = {(f16)v.x, (f16)v.y, (f16)v.z, (f16)v.w};
  *(f16x4*)(dst + (size_t)i * 4) = o;
}

// --------- pass 2: softmax row stats (m, l), key-split in 2 halves --------
__global__ __launch_bounds__(512, 2) void k_smstats(
    const f16* __restrict__ Qt, const f16* __restrict__ Kt,
    float* __restrict__ mpart, float* __restrict__ lpart) {
  int qt = blockIdx.x, ks = blockIdx.y, b = blockIdx.z;
  int tid = threadIdx.x;
  int wave = tid >> 6, lane = tid & 63, lq = lane & 15, quad = lane >> 4;
  int qbase = qt * 128;
  int kstart = ks * 2048;

  // Q fragments for this wave's 16 rows, whole C: 16 frags = 64 VGPRs
  f16x8 qf[16];
  {
    const f16* qrow = Qt + (size_t)(b * HW_ + qbase + wave * 16 + lq) * C_;
#pragma unroll
    for (int cs = 0; cs < 16; ++cs)
      qf[cs] = *(const f16x8*)(qrow + cs * 32 + quad * 8);
  }

  __shared__ __align__(16) f16 kl[64 * 520];  // 64 keys x 512 c (+8 pad)

  float m[4], l[4];
#pragma unroll
  for (int r = 0; r < 4; ++r) { m[r] = -INFINITY; l[r] = 0.f; }

  for (int ch = 0; ch < 32; ++ch) {
    int kb = kstart + ch * 64;
    __syncthreads();  // prior chunk's reads of kl done
#pragma unroll
    for (int r = 0; r < 8; ++r) {
      int row = wave * 8 + r;
      g2l16(Kt + (size_t)(b * HW_ + kb + row) * C_ + lane * 8,
            kl + row * 520 + lane * 8);
    }
    __syncthreads();  // staging visible (barrier drains vmcnt)

    f32x4 acc[4] = {{0, 0, 0, 0}, {0, 0, 0, 0}, {0, 0, 0, 0}, {0, 0, 0, 0}};
#pragma unroll
    for (int cs = 0; cs < 16; ++cs) {
#pragma unroll
      for (int nt = 0; nt < 4; ++nt) {
        f16x8 bf = *(const f16x8*)(kl + (nt * 16 + lq) * 520 + cs * 32 + quad * 8);
        acc[nt] = mfma16(qf[cs], bf, acc[nt]);
      }
    }
    // online (m, l) update; rows = quad*4 + r, 16 lanes of quad hold 16 cols/tile
#pragma unroll
    for (int r = 0; r < 4; ++r) {
      float cm = fmaxf(fmaxf(acc[0][r], acc[1][r]), fmaxf(acc[2][r], acc[3][r]));
#pragma unroll
      for (int msk = 1; msk < 16; msk <<= 1) cm = fmaxf(cm, __shfl_xor(cm, msk));
      float nm = fmaxf(m[r], cm);
      float se = __expf(acc[0][r] - nm) + __expf(acc[1][r] - nm) +
                 __expf(acc[2][r] - nm) + __expf(acc[3][r] - nm);
#pragma unroll
      for (int msk = 1; msk < 16; msk <<= 1) se += __shfl_xor(se, msk);
      l[r] = l[r] * __expf(m[r] - nm) + se;
      m[r] = nm;
    }
  }
  if (lq == 0) {
#pragma unroll
    for (int r = 0; r < 4; ++r) {
      int q = qbase + wave * 16 + quad * 4 + r;
      mpart[(ks * B_ + b) * HW_ + q] = m[r];
      lpart[(ks * B_ + b) * HW_ + q] = l[r];
    }
  }
}

// --- pass 3: fused S-recompute + exact softmax + P.V / P.V^2 + epilogue ---
// grid (qtile=64, ct=2, b). 8 waves = 4 q-groups x 2 key-halves.
// wave (qg,h): S rows qg*16..+16, key cols h*32..+32; PV channels ct*256+h*128..+128
__global__ __launch_bounds__(512, 2) void k_attn(
    const f16* __restrict__ Qt, const f16* __restrict__ Kt,
    const f16* __restrict__ Vh, const float* __restrict__ mpart,
    const float* __restrict__ lpart, const float* __restrict__ cx,
    const float2* __restrict__ cxs, float* __restrict__ out) {
  int qt = blockIdx.x, ct = blockIdx.y, b = blockIdx.z;
  int tid = threadIdx.x;
  int wave = tid >> 6, lane = tid & 63, lq = lane & 15, quad = lane >> 4;
  int qg = wave & 3, h = wave >> 2;
  int qbase = qt * 64;
  int chbase = ct * 256 + h * 128;

  f16x8 qf[16];
  {
    const f16* qrow = Qt + (size_t)(b * HW_ + qbase + qg * 16 + lq) * C_;
#pragma unroll
    for (int cs = 0; cs < 16; ++cs)
      qf[cs] = *(const f16x8*)(qrow + cs * 32 + quad * 8);
  }

  // merge key-split softmax partials -> exact (m, 1/l) per row
  float mrow[4], invl[4];
#pragma unroll
  for (int r = 0; r < 4; ++r) {
    int q = qbase + qg * 16 + quad * 4 + r;
    float m0 = mpart[(0 * B_ + b) * HW_ + q], m1 = mpart[(1 * B_ + b) * HW_ + q];
    float l0 = lpart[(0 * B_ + b) * HW_ + q], l1 = lpart[(1 * B_ + b) * HW_ + q];
    float mm = fmaxf(m0, m1);
    float ll = l0 * __expf(m0 - mm) + l1 * __expf(m1 - mm);
    mrow[r] = mm;
    invl[r] = 1.f / ll;
  }

  __shared__ __align__(16) f16 kl[64 * 520];  // K chunk: 64 keys x 512 c
  __shared__ __align__(16) f16 pl[64 * 72];   // P chunk: 64 q x 64 keys (+8 pad)

  f32x4 accM[8], accM2[8];
#pragma unroll
  for (int nt = 0; nt < 8; ++nt) {
    accM[nt] = (f32x4){0, 0, 0, 0};
    accM2[nt] = (f32x4){0, 0, 0, 0};
  }

  for (int chk = 0; chk < 64; ++chk) {
    int kb = chk * 64;
    __syncthreads();  // (A) prev chunk's kl S-reads + pl PV-reads done
#pragma unroll
    for (int r = 0; r < 8; ++r) {
      int row = wave * 8 + r;
      g2l16(Kt + (size_t)(b * HW_ + kb + row) * C_ + lane * 8,
            kl + row * 520 + lane * 8);
    }
    __syncthreads();  // (B) staging visible

    // S tile: this wave's 16 q x 32 keys
    f32x4 sacc[2] = {{0, 0, 0, 0}, {0, 0, 0, 0}};
#pragma unroll
    for (int cs = 0; cs < 16; ++cs) {
#pragma unroll
      for (int nt = 0; nt < 2; ++nt) {
        f16x8 bf =
            *(const f16x8*)(kl + (h * 32 + nt * 16 + lq) * 520 + cs * 32 + quad * 8);
        sacc[nt] = mfma16(qf[cs], bf, sacc[nt]);
      }
    }
    // exact P = exp(s - m) / l, C-layout -> LDS (A-layout friendly: [q][k])
#pragma unroll
    for (int nt = 0; nt < 2; ++nt) {
#pragma unroll
      for (int r = 0; r < 4; ++r) {
        float p = __expf(sacc[nt][r] - mrow[r]) * invl[r];
        pl[(qg * 16 + quad * 4 + r) * 72 + h * 32 + nt * 16 + lq] = (f16)p;
      }
    }
    __syncthreads();  // (C) P visible to all waves

    // PV: A = P rows of qg, B = V (and V^2) direct from global f16
#pragma unroll
    for (int ksp = 0; ksp < 2; ++ksp) {
      f16x8 af = *(const f16x8*)(pl + (qg * 16 + lq) * 72 + ksp * 32 + quad * 8);
#pragma unroll
      for (int nt = 0; nt < 8; ++nt) {
        const f16* vp = Vh + (size_t)(b * C_ + chbase + nt * 16 + lq) * HW_ + kb +
                        ksp * 32 + quad * 8;
        f16x8 vv = *(const f16x8*)vp;
        f16x8 v2 = vv * vv;
        accM[nt] = mfma16(af, vv, accM[nt]);
        accM2[nt] = mfma16(af, v2, accM2[nt]);
      }
    }
  }

  // epilogue: Var = M2 - M^2; out = sqrt(clip(Var)) * IN(c_x) + M
#pragma unroll
  for (int nt = 0; nt < 8; ++nt) {
    int chn = chbase + nt * 16 + lq;
    float2 st = cxs[b * C_ + chn];
#pragma unroll
    for (int r = 0; r < 4; ++r) {
      int q = qbase + qg * 16 + quad * 4 + r;
      float Mv = accM[nt][r];
      float Vv = accM2[nt][r] - Mv * Mv;
      float Sv = sqrtf(fmaxf(Vv, 1e-6f));
      size_t idx = (size_t)(b * C_ + chn) * HW_ + q;
      float nc = (cx[idx] - st.x) * st.y;
      out[idx] = Sv * nc + Mv;
    }
  }
}

// --------------------------------- host -----------------------------------
extern "C" void kernel_launch(void* const* d_in, const int* in_sizes, int n_in,
                              void* d_out, int out_size, void* d_ws,
                              size_t ws_size, hipStream_t stream) {
  const float* c_x = (const float*)d_in[0];
  const float* s_x = (const float*)d_in[1];
  const float* c1x = (const float*)d_in[2];
  const float* s1x = (const float*)d_in[3];
  float* out = (float*)d_out;

  char* ws = (char*)d_ws;
  const size_t T16 = (size_t)B_ * HW_ * C_ * sizeof(f16);  // 16 MiB
  f16* Qt = (f16*)(ws);
  f16* Kt = (f16*)(ws + T16);
  f16* Vh = (f16*)(ws + 2 * T16);
  float2* cxs = (float2*)(ws + 3 * T16);
  float2* c1s = cxs + B_ * C_;
  float2* s1s = c1s + B_ * C_;
  float* mpart = (float*)(s1s + B_ * C_);
  float* lpart = mpart + 2 * B_ * HW_;
  // total: 3*16 MiB + 48 KiB + 256 KiB ~= 48.3 MiB

  k_stats<<<dim3(C_, B_, 3), 256, 0, stream>>>(c_x, c1x, s1x, cxs, c1s, s1s);
  k_prept<<<dim3(HW_ / 64, C_ / 64, B_), 256, 0, stream>>>(c1x, c1s, Qt);
  k_prept<<<dim3(HW_ / 64, C_ / 64, B_), 256, 0, stream>>>(s1x, s1s, Kt);
  k_prepv<<<dim3(B_ * C_ * HW_ / 4 / 256), 256, 0, stream>>>(s_x, Vh);
  k_smstats<<<dim3(HW_ / 128, 2, B_), 512, 0, stream>>>(Qt, Kt, mpart, lpart);
  k_attn<<<dim3(HW_ / 64, 2, B_), 512, 0, stream>>>(Qt, Kt, Vh, mpart, lpart,
                                                    c_x, cxs, out);
}

// Round 2
// 1036.655 us; speedup vs baseline: 1.0234x; 1.0234x over previous
//
#include <hip/hip_runtime.h>
#include <cmath>

// AdaAttnNoConv: b=4, C=512, hw=4096 (fp32 in/out).
// out[b][v][q] = S[q][v] * IN(c_x)[b][v][q] + M[q][v]
//   A = softmax_k( IN(c_1x)^T[q][c] . IN(s_1x)[c][k] )
//   M = A V, Var = A V^2 - M^2, S = sqrt(clip(Var,1e-6)), V[k][v] = s_x[b][v][k]
//
// Round 2: single-pass flash attention (online softmax, unnormalized P,
// deferred 1/l), 256-thr blocks, double-buffered K staging via
// global_load_lds, 2 barriers/chunk. No stats kernel.

#define B_  4
#define C_  512
#define HW_ 4096
#define CK  32           // keys per chunk
#define NCHK (HW_ / CK)  // 128 chunks
#define KST (CK * 520)   // f16 elems per K buffer (row stride 520 = 512+8)

typedef _Float16 f16;
typedef _Float16 f16x8 __attribute__((ext_vector_type(8)));
typedef _Float16 f16x4 __attribute__((ext_vector_type(4)));
typedef float    f32x4 __attribute__((ext_vector_type(4)));

// Verified gfx950 fragment layouts (learn_hip m89/m91/m120, round-1 pass):
//  A[m][k]: m = lane&15, k = quad*8 + j
//  B[k][n]: n = lane&15, k = quad*8 + j
//  C/D[m][n]: n = lane&15, m = quad*4 + reg
__device__ __forceinline__ f32x4 mfma16(f16x8 a, f16x8 b, f32x4 c) {
  return __builtin_amdgcn_mfma_f32_16x16x32_f16(a, b, c, 0, 0, 0);
}

__device__ __forceinline__ void g2l16(const f16* g, f16* l) {
  __builtin_amdgcn_global_load_lds(
      (const __attribute__((address_space(1))) void*)g,
      (__attribute__((address_space(3))) void*)l, 16, 0, 0);
}

// ---------------- pass 0: instance-norm stats (mean, rstd) ----------------
__global__ __launch_bounds__(256) void k_stats(
    const float* __restrict__ cx, const float* __restrict__ c1,
    const float* __restrict__ s1,
    float2* __restrict__ cxs, float2* __restrict__ c1s, float2* __restrict__ s1s) {
  int c = blockIdx.x, b = blockIdx.y, t = blockIdx.z;
  const float* src = (t == 0 ? cx : (t == 1 ? c1 : s1)) + (size_t)(b * C_ + c) * HW_;
  float s = 0.f, q = 0.f;
  const float4* src4 = (const float4*)src;
  for (int i = threadIdx.x; i < HW_ / 4; i += 256) {
    float4 v = src4[i];
    s += v.x + v.y + v.z + v.w;
    q += v.x * v.x + v.y * v.y + v.z * v.z + v.w * v.w;
  }
#pragma unroll
  for (int off = 1; off < 64; off <<= 1) {
    s += __shfl_xor(s, off);
    q += __shfl_xor(q, off);
  }
  __shared__ float ss[4], sq[4];
  int wv = threadIdx.x >> 6;
  if ((threadIdx.x & 63) == 0) { ss[wv] = s; sq[wv] = q; }
  __syncthreads();
  if (threadIdx.x == 0) {
    float S = ss[0] + ss[1] + ss[2] + ss[3];
    float Q = sq[0] + sq[1] + sq[2] + sq[3];
    float mean = S * (1.f / HW_);
    float var = Q * (1.f / HW_) - mean * mean;
    float2 r;
    r.x = mean;
    r.y = rsqrtf(var + 1e-5f);
    (t == 0 ? cxs : (t == 1 ? c1s : s1s))[b * C_ + c] = r;
  }
}

// ------- pass 1: normalize + transpose (b,c,p) f32 -> (b,p,c) f16 ---------
__global__ __launch_bounds__(256) void k_prept(
    const float* __restrict__ src, const float2* __restrict__ st,
    f16* __restrict__ dst) {
  int pb = blockIdx.x * 64, cb = blockIdx.y * 64, b = blockIdx.z;
  __shared__ float t[64][65];
  int tj = threadIdx.x & 63, tr = threadIdx.x >> 6;
#pragma unroll 4
  for (int p = 0; p < 16; ++p) {
    int cl = p * 4 + tr;
    float2 mr = st[b * C_ + cb + cl];
    float v = src[(size_t)(b * C_ + cb + cl) * HW_ + pb + tj];
    t[cl][tj] = (v - mr.x) * mr.y;
  }
  __syncthreads();
#pragma unroll 4
  for (int p = 0; p < 16; ++p) {
    int pr = p * 4 + tr;
    dst[(size_t)(b * HW_ + pb + pr) * C_ + cb + tj] = (f16)t[tj][pr];
  }
}

// ---------------- pass 1b: V = s_x -> f16 (same layout) -------------------
__global__ __launch_bounds__(256) void k_prepv(const float* __restrict__ src,
                                               f16* __restrict__ dst) {
  int i = blockIdx.x * 256 + threadIdx.x;
  float4 v = ((const float4*)src)[i];
  f16x4 o = {(f16)v.x, (f16)v.y, (f16)v.z, (f16)v.w};
  *(f16x4*)(dst + (size_t)i * 4) = o;
}

// ------------------- pass 2: fused flash attention ------------------------
// grid (qt=128, ct=2, b=4); 256 thr = 4 waves; wave w: qg=w&1, h=w>>1.
// wave (qg,h): S-tile rows qg*16..+16, keys h*16..+16 of 32-chunk;
//              PV channels ct*256 + h*128 .. +128 for rows qg*16..+16.
__global__ __launch_bounds__(256, 2) void k_flash(
    const f16* __restrict__ Qt, const f16* __restrict__ Kt,
    const f16* __restrict__ Vh, const float* __restrict__ cx,
    const float2* __restrict__ cxs, float* __restrict__ out) {
  int qt = blockIdx.x, ct = blockIdx.y, b = blockIdx.z;
  int tid = threadIdx.x;
  int wave = tid >> 6, lane = tid & 63, lq = lane & 15, quad = lane >> 4;
  int qg = wave & 1, h = wave >> 1;
  int qbase = qt * 32;
  int chbase = ct * 256 + h * 128;

  __shared__ __align__(16) f16 kl[2 * KST];  // double-buffered K chunk
  __shared__ __align__(16) f16 pl[32 * 40];  // P: 32q x 32k (+8 pad)
  __shared__ float2 stats[2 * 32];           // per-h (m, sumexp) per q-row

  // Q fragments: rows qg*16+lq, full C (16 frags = 64 VGPR)
  f16x8 qf[16];
  {
    const f16* qrow = Qt + (size_t)(b * HW_ + qbase + qg * 16 + lq) * C_;
#pragma unroll
    for (int cs = 0; cs < 16; ++cs)
      qf[cs] = *(const f16x8*)(qrow + cs * 32 + quad * 8);
  }

  f32x4 accM[8], accM2[8];
#pragma unroll
  for (int nt = 0; nt < 8; ++nt) {
    accM[nt] = (f32x4){0, 0, 0, 0};
    accM2[nt] = (f32x4){0, 0, 0, 0};
  }
  float mrun[4], lrun[4];
#pragma unroll
  for (int r = 0; r < 4; ++r) { mrun[r] = -1e30f; lrun[r] = 0.f; }

  // prefetch chunk 0 into buffer 0
#pragma unroll
  for (int r = 0; r < 8; ++r)
    g2l16(Kt + (size_t)(b * HW_ + wave * 8 + r) * C_ + lane * 8,
          kl + (wave * 8 + r) * 520 + lane * 8);
  __syncthreads();  // drains vmcnt: buffer 0 ready

  for (int chk = 0; chk < NCHK; ++chk) {
    int kb = chk * CK;
    const f16* kcur = kl + (chk & 1) * KST;
    f16* knxt = kl + ((chk + 1) & 1) * KST;

    // prefetch next chunk early: full-chunk latency window
    if (chk + 1 < NCHK) {
      int kb2 = kb + CK;
#pragma unroll
      for (int r = 0; r < 8; ++r)
        g2l16(Kt + (size_t)(b * HW_ + kb2 + wave * 8 + r) * C_ + lane * 8,
              knxt + (wave * 8 + r) * 520 + lane * 8);
    }

    // S: 16q x 16k
    f32x4 sacc = (f32x4){0, 0, 0, 0};
#pragma unroll
    for (int cs = 0; cs < 16; ++cs) {
      f16x8 bf = *(const f16x8*)(kcur + (h * 16 + lq) * 520 + cs * 32 + quad * 8);
      sacc = mfma16(qf[cs], bf, sacc);
    }

    // per-h chunk stats: row max + sumexp (reduce over 16 lq lanes)
    float mh[4], er[4], ls[4];
#pragma unroll
    for (int r = 0; r < 4; ++r) {
      float cm = sacc[r];
#pragma unroll
      for (int msk = 1; msk < 16; msk <<= 1) cm = fmaxf(cm, __shfl_xor(cm, msk));
      mh[r] = cm;
      er[r] = __expf(sacc[r] - cm);
      float se = er[r];
#pragma unroll
      for (int msk = 1; msk < 16; msk <<= 1) se += __shfl_xor(se, msk);
      ls[r] = se;
    }
    if (lq == 0) {
#pragma unroll
      for (int r = 0; r < 4; ++r)
        stats[h * 32 + qg * 16 + quad * 4 + r] = make_float2(mh[r], ls[r]);
    }
    __syncthreads();  // B1: stats visible; kcur reads complete

    // merge halves, update running (m, l), rescale acc, write unnormalized P
    float al[4];
#pragma unroll
    for (int r = 0; r < 4; ++r) {
      int qr = qg * 16 + quad * 4 + r;
      float2 s0 = stats[qr], s1 = stats[32 + qr];
      float mc = fmaxf(s0.x, s1.x);
      float lc = s0.y * __expf(s0.x - mc) + s1.y * __expf(s1.x - mc);
      float mnew = fmaxf(mrun[r], mc);
      al[r] = __expf(mrun[r] - mnew);
      lrun[r] = lrun[r] * al[r] + lc * __expf(mc - mnew);
      float beta = __expf(mh[r] - mnew);
      pl[qr * 40 + h * 16 + lq] = (f16)(er[r] * beta);
      mrun[r] = mnew;
    }
    float amin = fminf(fminf(al[0], al[1]), fminf(al[2], al[3]));
    if (__any(amin < 1.0f)) {
#pragma unroll
      for (int nt = 0; nt < 8; ++nt) {
#pragma unroll
        for (int r = 0; r < 4; ++r) {
          accM[nt][r] *= al[r];
          accM2[nt][r] *= al[r];
        }
      }
    }
    __syncthreads();  // B2: P visible; next K chunk staged (vmcnt drained)

    // PV: A = P rows qg (16q x 32k, one frag), B = V / V^2 from global
    f16x8 af = *(const f16x8*)(pl + (qg * 16 + lq) * 40 + quad * 8);
#pragma unroll
    for (int nt = 0; nt < 8; ++nt) {
      const f16* vp =
          Vh + (size_t)(b * C_ + chbase + nt * 16 + lq) * HW_ + kb + quad * 8;
      f16x8 vv = *(const f16x8*)vp;
      f16x8 v2 = vv * vv;
      accM[nt] = mfma16(af, vv, accM[nt]);
      accM2[nt] = mfma16(af, v2, accM2[nt]);
    }
  }

  // epilogue: M = accM/l, Var = accM2/l - M^2; out = sqrt(clip)*IN(cx) + M
  float invl[4];
#pragma unroll
  for (int r = 0; r < 4; ++r) invl[r] = 1.0f / lrun[r];
  int q0 = qbase + qg * 16 + quad * 4;
#pragma unroll
  for (int nt = 0; nt < 8; ++nt) {
    int ch = chbase + nt * 16 + lq;
    float2 st = cxs[b * C_ + ch];
    size_t base = (size_t)(b * C_ + ch) * HW_ + q0;
    float4 cv = *(const float4*)(cx + base);
    float4 o;
    {
      float Mv = accM[nt][0] * invl[0];
      float Vv = accM2[nt][0] * invl[0] - Mv * Mv;
      o.x = sqrtf(fmaxf(Vv, 1e-6f)) * ((cv.x - st.x) * st.y) + Mv;
    }
    {
      float Mv = accM[nt][1] * invl[1];
      float Vv = accM2[nt][1] * invl[1] - Mv * Mv;
      o.y = sqrtf(fmaxf(Vv, 1e-6f)) * ((cv.y - st.x) * st.y) + Mv;
    }
    {
      float Mv = accM[nt][2] * invl[2];
      float Vv = accM2[nt][2] * invl[2] - Mv * Mv;
      o.z = sqrtf(fmaxf(Vv, 1e-6f)) * ((cv.z - st.x) * st.y) + Mv;
    }
    {
      float Mv = accM[nt][3] * invl[3];
      float Vv = accM2[nt][3] * invl[3] - Mv * Mv;
      o.w = sqrtf(fmaxf(Vv, 1e-6f)) * ((cv.w - st.x) * st.y) + Mv;
    }
    *(float4*)(out + base) = o;
  }
}

// --------------------------------- host -----------------------------------
extern "C" void kernel_launch(void* const* d_in, const int* in_sizes, int n_in,
                              void* d_out, int out_size, void* d_ws,
                              size_t ws_size, hipStream_t stream) {
  const float* c_x = (const float*)d_in[0];
  const float* s_x = (const float*)d_in[1];
  const float* c1x = (const float*)d_in[2];
  const float* s1x = (const float*)d_in[3];
  float* out = (float*)d_out;

  char* ws = (char*)d_ws;
  const size_t T16 = (size_t)B_ * HW_ * C_ * sizeof(f16);  // 16 MiB
  f16* Qt = (f16*)(ws);
  f16* Kt = (f16*)(ws + T16);
  f16* Vh = (f16*)(ws + 2 * T16);
  float2* cxs = (float2*)(ws + 3 * T16);
  float2* c1s = cxs + B_ * C_;
  float2* s1s = c1s + B_ * C_;
  // total: 3*16 MiB + 48 KiB

  k_stats<<<dim3(C_, B_, 3), 256, 0, stream>>>(c_x, c1x, s1x, cxs, c1s, s1s);
  k_prept<<<dim3(HW_ / 64, C_ / 64, B_), 256, 0, stream>>>(c1x, c1s, Qt);
  k_prept<<<dim3(HW_ / 64, C_ / 64, B_), 256, 0, stream>>>(s1x, s1s, Kt);
  k_prepv<<<dim3(B_ * C_ * HW_ / 4 / 256), 256, 0, stream>>>(s_x, Vh);
  k_flash<<<dim3(HW_ / 32, 2, B_), 256, 0, stream>>>(Qt, Kt, Vh, c_x, cxs, out);
}

// Round 3
// 614.454 us; speedup vs baseline: 1.7266x; 1.6871x over previous
//
#include <hip/hip_runtime.h>
#include <cmath>

// AdaAttnNoConv: b=4, C=512, hw=4096 (fp32 in/out).
// Round 3: two m97-shape GEMMs with materialized exp-shifted scores.
//   k_qk : S-tile GEMM, epilogue stores E = exp(s - m_tile) f16 + (m_t, l_t)
//   k_red: exact softmax merge -> alpha[row][ktile] = exp(m_t - m)/l
//   k_pexp: P = E * alpha (in-place, packed f16 mul)
//   k_pv : P x Vcat GEMM (Vcat channels interleaved: 2c=V, 2c+1=V^2),
//          fused epilogue sqrt(clip(M2-M^2))*IN(c_x)+M.

#define B_  4
#define C_  512
#define HW_ 4096

typedef _Float16 f16;
typedef _Float16 f16x8 __attribute__((ext_vector_type(8)));
typedef float    f32x4 __attribute__((ext_vector_type(4)));

// Verified gfx950 fragment layouts (learn_hip m89/m91, rounds 1-2 passed):
//  A[m][k]: m = lane&15, k = quad*8 + j
//  B[k][n]: n = lane&15, k = quad*8 + j
//  C/D[m][n]: n = lane&15, m = quad*4 + reg
__device__ __forceinline__ f32x4 mfma16(f16x8 a, f16x8 b, f32x4 c) {
  return __builtin_amdgcn_mfma_f32_16x16x32_f16(a, b, c, 0, 0, 0);
}
__device__ __forceinline__ void g2l16(const f16* g, f16* l) {
  __builtin_amdgcn_global_load_lds(
      (const __attribute__((address_space(1))) void*)g,
      (__attribute__((address_space(3))) void*)l, 16, 0, 0);
}

// ---------------- pass 0: instance-norm stats (mean, rstd) ----------------
__global__ __launch_bounds__(256) void k_stats(
    const float* __restrict__ cx, const float* __restrict__ c1,
    const float* __restrict__ s1,
    float2* __restrict__ cxs, float2* __restrict__ c1s, float2* __restrict__ s1s) {
  int c = blockIdx.x, b = blockIdx.y, t = blockIdx.z;
  const float* src = (t == 0 ? cx : (t == 1 ? c1 : s1)) + (size_t)(b * C_ + c) * HW_;
  float s = 0.f, q = 0.f;
  const float4* src4 = (const float4*)src;
  for (int i = threadIdx.x; i < HW_ / 4; i += 256) {
    float4 v = src4[i];
    s += v.x + v.y + v.z + v.w;
    q += v.x * v.x + v.y * v.y + v.z * v.z + v.w * v.w;
  }
#pragma unroll
  for (int off = 1; off < 64; off <<= 1) {
    s += __shfl_xor(s, off);
    q += __shfl_xor(q, off);
  }
  __shared__ float ss[4], sq[4];
  int wv = threadIdx.x >> 6;
  if ((threadIdx.x & 63) == 0) { ss[wv] = s; sq[wv] = q; }
  __syncthreads();
  if (threadIdx.x == 0) {
    float S = ss[0] + ss[1] + ss[2] + ss[3];
    float Q = sq[0] + sq[1] + sq[2] + sq[3];
    float mean = S * (1.f / HW_);
    float var = Q * (1.f / HW_) - mean * mean;
    float2 r;
    r.x = mean;
    r.y = rsqrtf(var + 1e-5f);
    (t == 0 ? cxs : (t == 1 ? c1s : s1s))[b * C_ + c] = r;
  }
}

// ------- pass 1: normalize + transpose (b,c,p) f32 -> (b,p,c) f16 ---------
__global__ __launch_bounds__(256) void k_prept(
    const float* __restrict__ src, const float2* __restrict__ st,
    f16* __restrict__ dst) {
  int pb = blockIdx.x * 64, cb = blockIdx.y * 64, b = blockIdx.z;
  __shared__ float t[64][65];
  int tj = threadIdx.x & 63, tr = threadIdx.x >> 6;
#pragma unroll 4
  for (int p = 0; p < 16; ++p) {
    int cl = p * 4 + tr;
    float2 mr = st[b * C_ + cb + cl];
    float v = src[(size_t)(b * C_ + cb + cl) * HW_ + pb + tj];
    t[cl][tj] = (v - mr.x) * mr.y;
  }
  __syncthreads();
#pragma unroll 4
  for (int p = 0; p < 16; ++p) {
    int pr = p * 4 + tr;
    dst[(size_t)(b * HW_ + pb + pr) * C_ + cb + tj] = (f16)t[tj][pr];
  }
}

// ---- pass 1b: Vcat[b][2c][k] = V, Vcat[b][2c+1][k] = V^2 (f16) -----------
__global__ __launch_bounds__(256) void k_prepv(const float* __restrict__ src,
                                               f16* __restrict__ vcat) {
  int gid = blockIdx.x * 256 + threadIdx.x;  // over B_*C_*HW_/8
  int bc = gid >> 9;
  int ko = (gid & 511) * 8;
  const float4* s = (const float4*)(src + (size_t)bc * HW_ + ko);
  float4 v0 = s[0], v1 = s[1];
  f16x8 v = {(f16)v0.x, (f16)v0.y, (f16)v0.z, (f16)v0.w,
             (f16)v1.x, (f16)v1.y, (f16)v1.z, (f16)v1.w};
  f16x8 v2 = v * v;
  int b = bc >> 9, c = bc & 511;
  f16* d = vcat + ((size_t)(b * 1024 + 2 * c)) * HW_ + ko;
  *(f16x8*)d = v;
  *(f16x8*)(d + HW_) = v2;
}

// ------------- pass 2: QK^T GEMM + exp-shifted score store ---------------
// grid (kt=32, qt=qspan/128, nb), 256 thr, 4 waves 2x2, 128x128 tile, BK=32.
__global__ __launch_bounds__(256) void k_qk(
    const f16* __restrict__ Qt, const f16* __restrict__ Kt,
    f16* __restrict__ E, float2* __restrict__ mlpart, int qspan) {
  int kt = blockIdx.x, qt = blockIdx.y, bz = blockIdx.z;
  const f16* Aq = Qt + (size_t)bz * HW_ * C_ + (size_t)qt * 128 * C_;
  const f16* Bk = Kt + (size_t)bz * HW_ * C_ + (size_t)kt * 128 * C_;
  f16* Eb = E + ((size_t)(bz * qspan + qt * 128)) * HW_ + kt * 128;
  float2* mlb = mlpart + ((size_t)(bz * qspan + qt * 128)) * 32 + kt;

  __shared__ __align__(16) f16 As[128 * 32], Bs[128 * 32];
  __shared__ float sred[2][128];

  int t = threadIdx.x, wave = t >> 6, lane = t & 63, lq = lane & 15, quad = lane >> 4;
  int wy = wave >> 1, wx = wave & 1;
  int srow = t >> 2, scol = (t & 3) * 8;

  f32x4 acc[4][4];
#pragma unroll
  for (int mt = 0; mt < 4; ++mt)
#pragma unroll
    for (int nt = 0; nt < 4; ++nt) acc[mt][nt] = (f32x4){0, 0, 0, 0};

  for (int kc = 0; kc < 16; ++kc) {
    __syncthreads();
    g2l16(Aq + (size_t)srow * C_ + kc * 32 + scol, As + t * 8);
    g2l16(Aq + (size_t)(srow + 64) * C_ + kc * 32 + scol, As + 2048 + t * 8);
    g2l16(Bk + (size_t)srow * C_ + kc * 32 + scol, Bs + t * 8);
    g2l16(Bk + (size_t)(srow + 64) * C_ + kc * 32 + scol, Bs + 2048 + t * 8);
    __syncthreads();
    f16x8 af[4], bf[4];
#pragma unroll
    for (int mt = 0; mt < 4; ++mt)
      af[mt] = *(const f16x8*)(As + (wy * 64 + mt * 16 + lq) * 32 + quad * 8);
#pragma unroll
    for (int nt = 0; nt < 4; ++nt)
      bf[nt] = *(const f16x8*)(Bs + (wx * 64 + nt * 16 + lq) * 32 + quad * 8);
#pragma unroll
    for (int mt = 0; mt < 4; ++mt)
#pragma unroll
      for (int nt = 0; nt < 4; ++nt)
        acc[mt][nt] = mfma16(af[mt], bf[nt], acc[mt][nt]);
  }

  // ---- epilogue: tile row-max, E = exp(s - m_t), row-sum partials ----
  float rmax[4][4];
#pragma unroll
  for (int mt = 0; mt < 4; ++mt)
#pragma unroll
    for (int r = 0; r < 4; ++r) {
      float v = fmaxf(fmaxf(acc[mt][0][r], acc[mt][1][r]),
                      fmaxf(acc[mt][2][r], acc[mt][3][r]));
#pragma unroll
      for (int msk = 1; msk < 16; msk <<= 1) v = fmaxf(v, __shfl_xor(v, msk));
      rmax[mt][r] = v;
    }
  if (lq == 0) {
#pragma unroll
    for (int mt = 0; mt < 4; ++mt)
#pragma unroll
      for (int r = 0; r < 4; ++r)
        sred[wx][wy * 64 + mt * 16 + quad * 4 + r] = rmax[mt][r];
  }
  __syncthreads();
  float mrow[4][4];
#pragma unroll
  for (int mt = 0; mt < 4; ++mt)
#pragma unroll
    for (int r = 0; r < 4; ++r) {
      int rr = wy * 64 + mt * 16 + quad * 4 + r;
      mrow[mt][r] = fmaxf(sred[0][rr], sred[1][rr]);
    }
  __syncthreads();  // sred reads done before reuse

  float rsum[4][4];
#pragma unroll
  for (int mt = 0; mt < 4; ++mt)
#pragma unroll
    for (int r = 0; r < 4; ++r) rsum[mt][r] = 0.f;
#pragma unroll
  for (int mt = 0; mt < 4; ++mt)
#pragma unroll
    for (int nt = 0; nt < 4; ++nt) {
      f32x4 v = acc[mt][nt];
#pragma unroll
      for (int r = 0; r < 4; ++r) {
        float e = __expf(v[r] - mrow[mt][r]);
        rsum[mt][r] += e;
        Eb[(size_t)(wy * 64 + mt * 16 + quad * 4 + r) * HW_ +
           wx * 64 + nt * 16 + lq] = (f16)e;
      }
    }
#pragma unroll
  for (int mt = 0; mt < 4; ++mt)
#pragma unroll
    for (int r = 0; r < 4; ++r) {
      float v = rsum[mt][r];
#pragma unroll
      for (int msk = 1; msk < 16; msk <<= 1) v += __shfl_xor(v, msk);
      rsum[mt][r] = v;
    }
  if (lq == 0) {
#pragma unroll
    for (int mt = 0; mt < 4; ++mt)
#pragma unroll
      for (int r = 0; r < 4; ++r)
        sred[wx][wy * 64 + mt * 16 + quad * 4 + r] = rsum[mt][r];
  }
  __syncthreads();
  if (wx == 0 && lq == 0) {
#pragma unroll
    for (int mt = 0; mt < 4; ++mt)
#pragma unroll
      for (int r = 0; r < 4; ++r) {
        int rr = wy * 64 + mt * 16 + quad * 4 + r;
        mlb[(size_t)rr * 32] = make_float2(mrow[mt][r], sred[0][rr] + sred[1][rr]);
      }
  }
}

// ---- pass 3: exact softmax merge -> alpha[row][kt] = exp(m_t-m)/l --------
__global__ __launch_bounds__(256) void k_red(const float2* __restrict__ mlpart,
                                             f16* __restrict__ alpha) {
  int row = blockIdx.x * 256 + threadIdx.x;
  const float2* p = mlpart + (size_t)row * 32;
  float2 loc[32];
  float m = -1e30f;
#pragma unroll
  for (int i = 0; i < 32; ++i) {
    loc[i] = p[i];
    m = fmaxf(m, loc[i].x);
  }
  float l = 0.f;
#pragma unroll
  for (int i = 0; i < 32; ++i) l += loc[i].y * __expf(loc[i].x - m);
  float invl = 1.f / l;
#pragma unroll
  for (int i = 0; i < 32; ++i)
    alpha[(size_t)row * 32 + i] = (f16)(__expf(loc[i].x - m) * invl);
}

// ---------------- pass 4: P = E * alpha (in-place) ------------------------
__global__ __launch_bounds__(256) void k_pexp(f16* __restrict__ E,
                                              const f16* __restrict__ alpha) {
  size_t gid = (size_t)blockIdx.x * 256 + threadIdx.x;
  size_t idx = gid * 8;
  size_t row = gid >> 9;          // HW/8 = 512 threads per row
  int ktl = ((int)gid >> 4) & 31; // 16 threads per 128-key tile
  f16 a = alpha[row * 32 + ktl];
  f16x8 v = *(f16x8*)(E + idx);
  v = v * a;
  *(f16x8*)(E + idx) = v;
}

// ------- pass 5: P x Vcat GEMM + fused variance/IN epilogue ---------------
// grid (ct=8, qt=qspan/128, nb). Vcat interleaved: ch2=2c -> V_c, 2c+1 -> V^2_c.
__global__ __launch_bounds__(256) void k_pv(
    const f16* __restrict__ P, const f16* __restrict__ Vcat,
    const float* __restrict__ cx, const float2* __restrict__ cxs,
    float* __restrict__ out, int qspan, int qbase) {
  int ct = blockIdx.x, qt = blockIdx.y, bz = blockIdx.z;
  const f16* Ap = P + ((size_t)(bz * qspan + qt * 128)) * HW_;
  const f16* Bv = Vcat + ((size_t)(bz * 1024 + ct * 128)) * HW_;

  __shared__ __align__(16) f16 As[128 * 32], Bs[128 * 32];
  int t = threadIdx.x, wave = t >> 6, lane = t & 63, lq = lane & 15, quad = lane >> 4;
  int wy = wave >> 1, wx = wave & 1;
  int srow = t >> 2, scol = (t & 3) * 8;

  f32x4 acc[4][4];
#pragma unroll
  for (int mt = 0; mt < 4; ++mt)
#pragma unroll
    for (int nt = 0; nt < 4; ++nt) acc[mt][nt] = (f32x4){0, 0, 0, 0};

  for (int kc = 0; kc < 128; ++kc) {
    __syncthreads();
    g2l16(Ap + (size_t)srow * HW_ + kc * 32 + scol, As + t * 8);
    g2l16(Ap + (size_t)(srow + 64) * HW_ + kc * 32 + scol, As + 2048 + t * 8);
    g2l16(Bv + (size_t)srow * HW_ + kc * 32 + scol, Bs + t * 8);
    g2l16(Bv + (size_t)(srow + 64) * HW_ + kc * 32 + scol, Bs + 2048 + t * 8);
    __syncthreads();
    f16x8 af[4], bf[4];
#pragma unroll
    for (int mt = 0; mt < 4; ++mt)
      af[mt] = *(const f16x8*)(As + (wy * 64 + mt * 16 + lq) * 32 + quad * 8);
#pragma unroll
    for (int nt = 0; nt < 4; ++nt)
      bf[nt] = *(const f16x8*)(Bs + (wx * 64 + nt * 16 + lq) * 32 + quad * 8);
#pragma unroll
    for (int mt = 0; mt < 4; ++mt)
#pragma unroll
      for (int nt = 0; nt < 4; ++nt)
        acc[mt][nt] = mfma16(af[mt], bf[nt], acc[mt][nt]);
  }

  // epilogue: even lanes hold M (ch2=2c), odd hold M2; pair via shfl_xor(1)
  int ch2base = ct * 128 + wx * 64;
#pragma unroll
  for (int mt = 0; mt < 4; ++mt) {
    int q0 = qbase + qt * 128 + wy * 64 + mt * 16 + quad * 4;
#pragma unroll
    for (int nt = 0; nt < 4; ++nt) {
      f32x4 m1 = acc[mt][nt];
      f32x4 m2;
#pragma unroll
      for (int r = 0; r < 4; ++r) m2[r] = __shfl_xor(m1[r], 1);
      if (!(lane & 1)) {
        int c = (ch2base + nt * 16 + lq) >> 1;
        float2 st = cxs[bz * C_ + c];
        size_t base = ((size_t)bz * C_ + c) * HW_ + q0;
        float4 cv = *(const float4*)(cx + base);
        float4 o;
        o.x = sqrtf(fmaxf(m2[0] - m1[0] * m1[0], 1e-6f)) * ((cv.x - st.x) * st.y) + m1[0];
        o.y = sqrtf(fmaxf(m2[1] - m1[1] * m1[1], 1e-6f)) * ((cv.y - st.x) * st.y) + m1[1];
        o.z = sqrtf(fmaxf(m2[2] - m1[2] * m1[2], 1e-6f)) * ((cv.z - st.x) * st.y) + m1[2];
        o.w = sqrtf(fmaxf(m2[3] - m1[3] * m1[3], 1e-6f)) * ((cv.w - st.x) * st.y) + m1[3];
        *(float4*)(out + base) = o;
      }
    }
  }
}

// --------------------------------- host -----------------------------------
extern "C" void kernel_launch(void* const* d_in, const int* in_sizes, int n_in,
                              void* d_out, int out_size, void* d_ws,
                              size_t ws_size, hipStream_t stream) {
  const float* c_x = (const float*)d_in[0];
  const float* s_x = (const float*)d_in[1];
  const float* c1x = (const float*)d_in[2];
  const float* s1x = (const float*)d_in[3];
  float* out = (float*)d_out;

  char* ws = (char*)d_ws;
  size_t o = 0;
  f16* Qt = (f16*)(ws + o);  o += (size_t)B_ * HW_ * C_ * 2;        // 16 MiB
  f16* Kt = (f16*)(ws + o);  o += (size_t)B_ * HW_ * C_ * 2;        // 16 MiB
  f16* Vcat = (f16*)(ws + o); o += (size_t)B_ * HW_ * 1024 * 2;     // 32 MiB
  float2* cxs = (float2*)(ws + o); o += B_ * C_ * sizeof(float2);
  float2* c1s = (float2*)(ws + o); o += B_ * C_ * sizeof(float2);
  float2* s1s = (float2*)(ws + o); o += B_ * C_ * sizeof(float2);
  size_t fixed = (o + 255) & ~(size_t)255;

  // score-region tier select: rows = nb*qspan; bytes/row = E + mlpart + alpha
  const size_t per_row = (size_t)HW_ * 2 + 32 * 8 + 32 * 2;
  struct Cfg { int nb, qs; };
  const Cfg cfgs[5] = {{4, 4096}, {1, 4096}, {1, 2048}, {1, 1024}, {1, 512}};
  Cfg cfg = cfgs[4];
  for (int i = 0; i < 5; ++i) {
    size_t rows = (size_t)cfgs[i].nb * cfgs[i].qs;
    if (fixed + rows * per_row <= ws_size) { cfg = cfgs[i]; break; }
  }
  const int nb = cfg.nb, qspan = cfg.qs;
  const size_t rows = (size_t)nb * qspan;
  f16* E = (f16*)(ws + fixed);
  float2* mlpart = (float2*)(ws + fixed + rows * HW_ * 2);
  f16* alpha = (f16*)(ws + fixed + rows * HW_ * 2 + rows * 32 * 8);

  k_stats<<<dim3(C_, B_, 3), 256, 0, stream>>>(c_x, c1x, s1x, cxs, c1s, s1s);
  k_prept<<<dim3(HW_ / 64, C_ / 64, B_), 256, 0, stream>>>(c1x, c1s, Qt);
  k_prept<<<dim3(HW_ / 64, C_ / 64, B_), 256, 0, stream>>>(s1x, s1s, Kt);
  k_prepv<<<dim3(B_ * C_ * HW_ / 8 / 256), 256, 0, stream>>>(s_x, Vcat);

  for (int b0 = 0; b0 < B_; b0 += nb) {
    for (int qb = 0; qb < HW_; qb += qspan) {
      const f16* Qtp = Qt + ((size_t)b0 * HW_ + qb) * C_;
      const f16* Ktp = Kt + (size_t)b0 * HW_ * C_;
      const f16* Vcp = Vcat + (size_t)b0 * 1024 * HW_;
      const float* cxp = c_x + (size_t)b0 * C_ * HW_;
      const float2* cxsp = cxs + b0 * C_;
      float* outp = out + (size_t)b0 * C_ * HW_;

      k_qk<<<dim3(HW_ / 128, qspan / 128, nb), 256, 0, stream>>>(
          Qtp, Ktp, E, mlpart, qspan);
      k_red<<<dim3((unsigned)(rows / 256)), 256, 0, stream>>>(mlpart, alpha);
      k_pexp<<<dim3((unsigned)(rows * 2)), 256, 0, stream>>>(E, alpha);
      k_pv<<<dim3(8, qspan / 128, nb), 256, 0, stream>>>(
          E, Vcp, cxp, cxsp, outp, qspan, qb);
    }
  }
}

// Round 4
// 498.225 us; speedup vs baseline: 2.1294x; 1.2333x over previous
//
#include <hip/hip_runtime.h>
#include <cmath>

// AdaAttnNoConv: b=4, C=512, hw=4096 (fp32 in/out).
// Round 4: k_pv gets XCD-clustered swizzle (P-tile L2 locality), 128x256
// tile, and in-kernel alpha (k_pexp eliminated).
//   k_qk : S-tile GEMM, epilogue stores E = exp(s - m_tile) f16 + (m_t, l_t)
//   k_red: exact softmax merge -> alpha[row][kt] = exp(m_t - m)/l  (f32)
//   k_pv : (E*alpha) x Vcat GEMM (Vcat: 2c=V, 2c+1=V^2), alpha applied to
//          A-frags from LDS, fused sqrt(clip(M2-M^2))*IN(c_x)+M epilogue.

#define B_  4
#define C_  512
#define HW_ 4096

typedef _Float16 f16;
typedef _Float16 f16x8 __attribute__((ext_vector_type(8)));
typedef float    f32x4 __attribute__((ext_vector_type(4)));

// Verified gfx950 fragment layouts (learn_hip m89/m91, rounds 1-3 passed):
//  A[m][k]: m = lane&15, k = quad*8 + j
//  B[k][n]: n = lane&15, k = quad*8 + j
//  C/D[m][n]: n = lane&15, m = quad*4 + reg
__device__ __forceinline__ f32x4 mfma16(f16x8 a, f16x8 b, f32x4 c) {
  return __builtin_amdgcn_mfma_f32_16x16x32_f16(a, b, c, 0, 0, 0);
}
__device__ __forceinline__ void g2l16(const f16* g, f16* l) {
  __builtin_amdgcn_global_load_lds(
      (const __attribute__((address_space(1))) void*)g,
      (__attribute__((address_space(3))) void*)l, 16, 0, 0);
}

// ---------------- pass 0: instance-norm stats (mean, rstd) ----------------
__global__ __launch_bounds__(256) void k_stats(
    const float* __restrict__ cx, const float* __restrict__ c1,
    const float* __restrict__ s1,
    float2* __restrict__ cxs, float2* __restrict__ c1s, float2* __restrict__ s1s) {
  int c = blockIdx.x, b = blockIdx.y, t = blockIdx.z;
  const float* src = (t == 0 ? cx : (t == 1 ? c1 : s1)) + (size_t)(b * C_ + c) * HW_;
  float s = 0.f, q = 0.f;
  const float4* src4 = (const float4*)src;
  for (int i = threadIdx.x; i < HW_ / 4; i += 256) {
    float4 v = src4[i];
    s += v.x + v.y + v.z + v.w;
    q += v.x * v.x + v.y * v.y + v.z * v.z + v.w * v.w;
  }
#pragma unroll
  for (int off = 1; off < 64; off <<= 1) {
    s += __shfl_xor(s, off);
    q += __shfl_xor(q, off);
  }
  __shared__ float ss[4], sq[4];
  int wv = threadIdx.x >> 6;
  if ((threadIdx.x & 63) == 0) { ss[wv] = s; sq[wv] = q; }
  __syncthreads();
  if (threadIdx.x == 0) {
    float S = ss[0] + ss[1] + ss[2] + ss[3];
    float Q = sq[0] + sq[1] + sq[2] + sq[3];
    float mean = S * (1.f / HW_);
    float var = Q * (1.f / HW_) - mean * mean;
    float2 r;
    r.x = mean;
    r.y = rsqrtf(var + 1e-5f);
    (t == 0 ? cxs : (t == 1 ? c1s : s1s))[b * C_ + c] = r;
  }
}

// ------- pass 1: normalize + transpose (b,c,p) f32 -> (b,p,c) f16 ---------
__global__ __launch_bounds__(256) void k_prept(
    const float* __restrict__ src, const float2* __restrict__ st,
    f16* __restrict__ dst) {
  int pb = blockIdx.x * 64, cb = blockIdx.y * 64, b = blockIdx.z;
  __shared__ float t[64][65];
  int tj = threadIdx.x & 63, tr = threadIdx.x >> 6;
#pragma unroll 4
  for (int p = 0; p < 16; ++p) {
    int cl = p * 4 + tr;
    float2 mr = st[b * C_ + cb + cl];
    float v = src[(size_t)(b * C_ + cb + cl) * HW_ + pb + tj];
    t[cl][tj] = (v - mr.x) * mr.y;
  }
  __syncthreads();
#pragma unroll 4
  for (int p = 0; p < 16; ++p) {
    int pr = p * 4 + tr;
    dst[(size_t)(b * HW_ + pb + pr) * C_ + cb + tj] = (f16)t[tj][pr];
  }
}

// ---- pass 1b: Vcat[b][2c][k] = V, Vcat[b][2c+1][k] = V^2 (f16) -----------
__global__ __launch_bounds__(256) void k_prepv(const float* __restrict__ src,
                                               f16* __restrict__ vcat) {
  int gid = blockIdx.x * 256 + threadIdx.x;  // over B_*C_*HW_/8
  int bc = gid >> 9;
  int ko = (gid & 511) * 8;
  const float4* s = (const float4*)(src + (size_t)bc * HW_ + ko);
  float4 v0 = s[0], v1 = s[1];
  f16x8 v = {(f16)v0.x, (f16)v0.y, (f16)v0.z, (f16)v0.w,
             (f16)v1.x, (f16)v1.y, (f16)v1.z, (f16)v1.w};
  f16x8 v2 = v * v;
  int b = bc >> 9, c = bc & 511;
  f16* d = vcat + ((size_t)(b * 1024 + 2 * c)) * HW_ + ko;
  *(f16x8*)d = v;
  *(f16x8*)(d + HW_) = v2;
}

// ------------- pass 2: QK^T GEMM + exp-shifted score store ---------------
// grid (kt=32, qt=qspan/128, nb), 256 thr, 4 waves 2x2, 128x128 tile, BK=32.
__global__ __launch_bounds__(256) void k_qk(
    const f16* __restrict__ Qt, const f16* __restrict__ Kt,
    f16* __restrict__ E, float2* __restrict__ mlpart, int qspan) {
  int kt = blockIdx.x, qt = blockIdx.y, bz = blockIdx.z;
  const f16* Aq = Qt + (size_t)bz * HW_ * C_ + (size_t)qt * 128 * C_;
  const f16* Bk = Kt + (size_t)bz * HW_ * C_ + (size_t)kt * 128 * C_;
  f16* Eb = E + ((size_t)(bz * qspan + qt * 128)) * HW_ + kt * 128;
  float2* mlb = mlpart + ((size_t)(bz * qspan + qt * 128)) * 32 + kt;

  __shared__ __align__(16) f16 As[128 * 32], Bs[128 * 32];
  __shared__ float sred[2][128];

  int t = threadIdx.x, wave = t >> 6, lane = t & 63, lq = lane & 15, quad = lane >> 4;
  int wy = wave >> 1, wx = wave & 1;
  int srow = t >> 2, scol = (t & 3) * 8;

  f32x4 acc[4][4];
#pragma unroll
  for (int mt = 0; mt < 4; ++mt)
#pragma unroll
    for (int nt = 0; nt < 4; ++nt) acc[mt][nt] = (f32x4){0, 0, 0, 0};

  for (int kc = 0; kc < 16; ++kc) {
    __syncthreads();
    g2l16(Aq + (size_t)srow * C_ + kc * 32 + scol, As + t * 8);
    g2l16(Aq + (size_t)(srow + 64) * C_ + kc * 32 + scol, As + 2048 + t * 8);
    g2l16(Bk + (size_t)srow * C_ + kc * 32 + scol, Bs + t * 8);
    g2l16(Bk + (size_t)(srow + 64) * C_ + kc * 32 + scol, Bs + 2048 + t * 8);
    __syncthreads();
    f16x8 af[4], bf[4];
#pragma unroll
    for (int mt = 0; mt < 4; ++mt)
      af[mt] = *(const f16x8*)(As + (wy * 64 + mt * 16 + lq) * 32 + quad * 8);
#pragma unroll
    for (int nt = 0; nt < 4; ++nt)
      bf[nt] = *(const f16x8*)(Bs + (wx * 64 + nt * 16 + lq) * 32 + quad * 8);
#pragma unroll
    for (int mt = 0; mt < 4; ++mt)
#pragma unroll
      for (int nt = 0; nt < 4; ++nt)
        acc[mt][nt] = mfma16(af[mt], bf[nt], acc[mt][nt]);
  }

  // ---- epilogue: tile row-max, E = exp(s - m_t), row-sum partials ----
  float rmax[4][4];
#pragma unroll
  for (int mt = 0; mt < 4; ++mt)
#pragma unroll
    for (int r = 0; r < 4; ++r) {
      float v = fmaxf(fmaxf(acc[mt][0][r], acc[mt][1][r]),
                      fmaxf(acc[mt][2][r], acc[mt][3][r]));
#pragma unroll
      for (int msk = 1; msk < 16; msk <<= 1) v = fmaxf(v, __shfl_xor(v, msk));
      rmax[mt][r] = v;
    }
  if (lq == 0) {
#pragma unroll
    for (int mt = 0; mt < 4; ++mt)
#pragma unroll
      for (int r = 0; r < 4; ++r)
        sred[wx][wy * 64 + mt * 16 + quad * 4 + r] = rmax[mt][r];
  }
  __syncthreads();
  float mrow[4][4];
#pragma unroll
  for (int mt = 0; mt < 4; ++mt)
#pragma unroll
    for (int r = 0; r < 4; ++r) {
      int rr = wy * 64 + mt * 16 + quad * 4 + r;
      mrow[mt][r] = fmaxf(sred[0][rr], sred[1][rr]);
    }
  __syncthreads();  // sred reads done before reuse

  float rsum[4][4];
#pragma unroll
  for (int mt = 0; mt < 4; ++mt)
#pragma unroll
    for (int r = 0; r < 4; ++r) rsum[mt][r] = 0.f;
#pragma unroll
  for (int mt = 0; mt < 4; ++mt)
#pragma unroll
    for (int nt = 0; nt < 4; ++nt) {
      f32x4 v = acc[mt][nt];
#pragma unroll
      for (int r = 0; r < 4; ++r) {
        float e = __expf(v[r] - mrow[mt][r]);
        rsum[mt][r] += e;
        Eb[(size_t)(wy * 64 + mt * 16 + quad * 4 + r) * HW_ +
           wx * 64 + nt * 16 + lq] = (f16)e;
      }
    }
#pragma unroll
  for (int mt = 0; mt < 4; ++mt)
#pragma unroll
    for (int r = 0; r < 4; ++r) {
      float v = rsum[mt][r];
#pragma unroll
      for (int msk = 1; msk < 16; msk <<= 1) v += __shfl_xor(v, msk);
      rsum[mt][r] = v;
    }
  if (lq == 0) {
#pragma unroll
    for (int mt = 0; mt < 4; ++mt)
#pragma unroll
      for (int r = 0; r < 4; ++r)
        sred[wx][wy * 64 + mt * 16 + quad * 4 + r] = rsum[mt][r];
  }
  __syncthreads();
  if (wx == 0 && lq == 0) {
#pragma unroll
    for (int mt = 0; mt < 4; ++mt)
#pragma unroll
      for (int r = 0; r < 4; ++r) {
        int rr = wy * 64 + mt * 16 + quad * 4 + r;
        mlb[(size_t)rr * 32] = make_float2(mrow[mt][r], sred[0][rr] + sred[1][rr]);
      }
  }
}

// ---- pass 3: exact softmax merge -> alpha[row][kt] = exp(m_t-m)/l (f32) --
__global__ __launch_bounds__(256) void k_red(const float2* __restrict__ mlpart,
                                             float* __restrict__ alpha) {
  int row = blockIdx.x * 256 + threadIdx.x;
  const float2* p = mlpart + (size_t)row * 32;
  float2 loc[32];
  float m = -1e30f;
#pragma unroll
  for (int i = 0; i < 32; ++i) {
    loc[i] = p[i];
    m = fmaxf(m, loc[i].x);
  }
  float l = 0.f;
#pragma unroll
  for (int i = 0; i < 32; ++i) l += loc[i].y * __expf(loc[i].x - m);
  float invl = 1.f / l;
#pragma unroll
  for (int i = 0; i < 32; ++i)
    alpha[(size_t)row * 32 + i] = __expf(loc[i].x - m) * invl;
}

// ------- pass 4: (E*alpha) x Vcat GEMM + fused variance/IN epilogue -------
// 1D grid, XCD-clustered: each XCD owns npairs/8 q-tiles x all 4 ct tiles
// so a P-tile is fetched into ONE L2 and hit by its 4 ct-blocks.
// 128q x 256ch2 tile, 4 waves 2x2 (wy: q-half, wx: 128-ch2 half).
__global__ __launch_bounds__(256, 2) void k_pv(
    const f16* __restrict__ P, const float* __restrict__ alphaG,
    const f16* __restrict__ Vcat, const float* __restrict__ cx,
    const float2* __restrict__ cxs, float* __restrict__ out,
    int qspan, int qbase, int qt128) {
  int npairs = (int)gridDim.x >> 2;
  int id = blockIdx.x, pair, ct;
  if ((npairs & 7) == 0) {
    int x = id & 7, j = id >> 3, ppx = npairs >> 3;
    pair = x * ppx + (j >> 2);
    ct = j & 3;
  } else {
    pair = id >> 2;
    ct = id & 3;
  }
  int bz = pair / qt128, qt = pair - bz * qt128;

  const f16* Ap = P + ((size_t)(bz * qspan + qt * 128)) * HW_;
  const f16* Bv = Vcat + ((size_t)(bz * 1024 + ct * 256)) * HW_;

  __shared__ __align__(16) f16 As[128 * 32], Bs[256 * 32];
  __shared__ float Al[128 * 33];  // alpha, stride 33 -> conflict-free scalar reads

  int t = threadIdx.x, wave = t >> 6, lane = t & 63, lq = lane & 15, quad = lane >> 4;
  int wy = wave >> 1, wx = wave & 1;
  int srow = t >> 2, scol = (t & 3) * 8;

  // stage alpha for this block's 128 rows x 32 kt (coalesced f32 loads)
  {
    const float* ag = alphaG + ((size_t)(bz * qspan + qt * 128)) * 32;
#pragma unroll
    for (int i = 0; i < 16; ++i) {
      int e = i * 256 + t;
      Al[(e >> 5) * 33 + (e & 31)] = ag[e];
    }
  }

  f32x4 acc[4][8];
#pragma unroll
  for (int mt = 0; mt < 4; ++mt)
#pragma unroll
    for (int nt = 0; nt < 8; ++nt) acc[mt][nt] = (f32x4){0, 0, 0, 0};

  for (int kc = 0; kc < 128; ++kc) {
    __syncthreads();  // prev iter LDS reads done (also covers alpha stage @kc=0)
    g2l16(Ap + (size_t)srow * HW_ + kc * 32 + scol, As + t * 8);
    g2l16(Ap + (size_t)(srow + 64) * HW_ + kc * 32 + scol, As + 2048 + t * 8);
#pragma unroll
    for (int i = 0; i < 4; ++i)
      g2l16(Bv + (size_t)(srow + 64 * i) * HW_ + kc * 32 + scol,
            Bs + i * 2048 + t * 8);
    __syncthreads();  // staging visible

    int ktl = kc >> 2;
    f16x8 af[4];
    f16x8 bf[8];
#pragma unroll
    for (int mt = 0; mt < 4; ++mt) {
      af[mt] = *(const f16x8*)(As + (wy * 64 + mt * 16 + lq) * 32 + quad * 8);
      f16 a = (f16)Al[(wy * 64 + mt * 16 + lq) * 33 + ktl];
      af[mt] = af[mt] * a;  // fold softmax alpha into A-fragment
    }
#pragma unroll
    for (int nt = 0; nt < 8; ++nt)
      bf[nt] = *(const f16x8*)(Bs + (wx * 128 + nt * 16 + lq) * 32 + quad * 8);
#pragma unroll
    for (int mt = 0; mt < 4; ++mt)
#pragma unroll
      for (int nt = 0; nt < 8; ++nt)
        acc[mt][nt] = mfma16(af[mt], bf[nt], acc[mt][nt]);
  }

  // epilogue: even lanes hold M (ch2=2c), odd hold M2; pair via shfl_xor(1)
  int ch2base = ct * 256 + wx * 128;
#pragma unroll
  for (int mt = 0; mt < 4; ++mt) {
    int q0 = qbase + qt * 128 + wy * 64 + mt * 16 + quad * 4;
#pragma unroll
    for (int nt = 0; nt < 8; ++nt) {
      f32x4 m1 = acc[mt][nt];
      f32x4 m2;
#pragma unroll
      for (int r = 0; r < 4; ++r) m2[r] = __shfl_xor(m1[r], 1);
      if (!(lane & 1)) {
        int c = (ch2base + nt * 16 + lq) >> 1;
        float2 st = cxs[bz * C_ + c];
        size_t base = ((size_t)bz * C_ + c) * HW_ + q0;
        float4 cv = *(const float4*)(cx + base);
        float4 o;
        o.x = sqrtf(fmaxf(m2[0] - m1[0] * m1[0], 1e-6f)) * ((cv.x - st.x) * st.y) + m1[0];
        o.y = sqrtf(fmaxf(m2[1] - m1[1] * m1[1], 1e-6f)) * ((cv.y - st.x) * st.y) + m1[1];
        o.z = sqrtf(fmaxf(m2[2] - m1[2] * m1[2], 1e-6f)) * ((cv.z - st.x) * st.y) + m1[2];
        o.w = sqrtf(fmaxf(m2[3] - m1[3] * m1[3], 1e-6f)) * ((cv.w - st.x) * st.y) + m1[3];
        *(float4*)(out + base) = o;
      }
    }
  }
}

// --------------------------------- host -----------------------------------
extern "C" void kernel_launch(void* const* d_in, const int* in_sizes, int n_in,
                              void* d_out, int out_size, void* d_ws,
                              size_t ws_size, hipStream_t stream) {
  const float* c_x = (const float*)d_in[0];
  const float* s_x = (const float*)d_in[1];
  const float* c1x = (const float*)d_in[2];
  const float* s1x = (const float*)d_in[3];
  float* out = (float*)d_out;

  char* ws = (char*)d_ws;
  size_t o = 0;
  f16* Qt = (f16*)(ws + o);  o += (size_t)B_ * HW_ * C_ * 2;        // 16 MiB
  f16* Kt = (f16*)(ws + o);  o += (size_t)B_ * HW_ * C_ * 2;        // 16 MiB
  f16* Vcat = (f16*)(ws + o); o += (size_t)B_ * HW_ * 1024 * 2;     // 32 MiB
  float2* cxs = (float2*)(ws + o); o += B_ * C_ * sizeof(float2);
  float2* c1s = (float2*)(ws + o); o += B_ * C_ * sizeof(float2);
  float2* s1s = (float2*)(ws + o); o += B_ * C_ * sizeof(float2);
  size_t fixed = (o + 255) & ~(size_t)255;

  // score-region tiers: rows = nb*qspan; bytes/row = E + mlpart + alpha(f32)
  const size_t per_row = (size_t)HW_ * 2 + 32 * 8 + 32 * 4;
  struct Cfg { int nb, qs; };
  const Cfg cfgs[5] = {{4, 4096}, {1, 4096}, {1, 2048}, {1, 1024}, {1, 512}};
  Cfg cfg = cfgs[4];
  for (int i = 0; i < 5; ++i) {
    size_t rows = (size_t)cfgs[i].nb * cfgs[i].qs;
    if (fixed + rows * per_row <= ws_size) { cfg = cfgs[i]; break; }
  }
  const int nb = cfg.nb, qspan = cfg.qs, qt128 = qspan / 128;
  const size_t rows = (size_t)nb * qspan;
  f16* E = (f16*)(ws + fixed);
  float2* mlpart = (float2*)(ws + fixed + rows * HW_ * 2);
  float* alpha = (float*)(ws + fixed + rows * HW_ * 2 + rows * 32 * 8);

  k_stats<<<dim3(C_, B_, 3), 256, 0, stream>>>(c_x, c1x, s1x, cxs, c1s, s1s);
  k_prept<<<dim3(HW_ / 64, C_ / 64, B_), 256, 0, stream>>>(c1x, c1s, Qt);
  k_prept<<<dim3(HW_ / 64, C_ / 64, B_), 256, 0, stream>>>(s1x, s1s, Kt);
  k_prepv<<<dim3(B_ * C_ * HW_ / 8 / 256), 256, 0, stream>>>(s_x, Vcat);

  for (int b0 = 0; b0 < B_; b0 += nb) {
    for (int qb = 0; qb < HW_; qb += qspan) {
      const f16* Qtp = Qt + ((size_t)b0 * HW_ + qb) * C_;
      const f16* Ktp = Kt + (size_t)b0 * HW_ * C_;
      const f16* Vcp = Vcat + (size_t)b0 * 1024 * HW_;
      const float* cxp = c_x + (size_t)b0 * C_ * HW_;
      const float2* cxsp = cxs + b0 * C_;
      float* outp = out + (size_t)b0 * C_ * HW_;

      k_qk<<<dim3(HW_ / 128, qt128, nb), 256, 0, stream>>>(Qtp, Ktp, E,
                                                           mlpart, qspan);
      k_red<<<dim3((unsigned)(rows / 256)), 256, 0, stream>>>(mlpart, alpha);
      k_pv<<<dim3((unsigned)(nb * qt128 * 4)), 256, 0, stream>>>(
          E, alpha, Vcp, cxp, cxsp, outp, qspan, qb, qt128);
    }
  }
}

// Round 5
// 465.830 us; speedup vs baseline: 2.2774x; 1.0695x over previous
//
#include <hip/hip_runtime.h>
#include <cmath>

// AdaAttnNoConv: b=4, C=512, hw=4096 (fp32 in/out).
// Round 5: k_qk rebuilt to the k_pv recipe: 128x256 tile (32 MFMA/iter),
// XCD-clustered 1D swizzle (Q-tiles pinned per-XCD L2), epilogue widened.
// mlpart/alpha granularity: 16 tiles of 256 keys.
//   k_qk : S-tile GEMM, epilogue stores E = exp(s - m_tile) f16 + (m_t, l_t)
//   k_red: exact softmax merge -> alpha[row][kt16] = exp(m_t - m)/l  (f32)
//   k_pv : (E*alpha) x Vcat GEMM (Vcat: 2c=V, 2c+1=V^2), alpha on A-frags,
//          fused sqrt(clip(M2-M^2))*IN(c_x)+M epilogue. XCD-clustered.

#define B_  4
#define C_  512
#define HW_ 4096

typedef _Float16 f16;
typedef _Float16 f16x8 __attribute__((ext_vector_type(8)));
typedef float    f32x4 __attribute__((ext_vector_type(4)));

// Verified gfx950 fragment layouts (learn_hip m89/m91, rounds 1-4 passed):
//  A[m][k]: m = lane&15, k = quad*8 + j
//  B[k][n]: n = lane&15, k = quad*8 + j
//  C/D[m][n]: n = lane&15, m = quad*4 + reg
__device__ __forceinline__ f32x4 mfma16(f16x8 a, f16x8 b, f32x4 c) {
  return __builtin_amdgcn_mfma_f32_16x16x32_f16(a, b, c, 0, 0, 0);
}
__device__ __forceinline__ void g2l16(const f16* g, f16* l) {
  __builtin_amdgcn_global_load_lds(
      (const __attribute__((address_space(1))) void*)g,
      (__attribute__((address_space(3))) void*)l, 16, 0, 0);
}

// ---------------- pass 0: instance-norm stats (mean, rstd) ----------------
__global__ __launch_bounds__(256) void k_stats(
    const float* __restrict__ cx, const float* __restrict__ c1,
    const float* __restrict__ s1,
    float2* __restrict__ cxs, float2* __restrict__ c1s, float2* __restrict__ s1s) {
  int c = blockIdx.x, b = blockIdx.y, t = blockIdx.z;
  const float* src = (t == 0 ? cx : (t == 1 ? c1 : s1)) + (size_t)(b * C_ + c) * HW_;
  float s = 0.f, q = 0.f;
  const float4* src4 = (const float4*)src;
  for (int i = threadIdx.x; i < HW_ / 4; i += 256) {
    float4 v = src4[i];
    s += v.x + v.y + v.z + v.w;
    q += v.x * v.x + v.y * v.y + v.z * v.z + v.w * v.w;
  }
#pragma unroll
  for (int off = 1; off < 64; off <<= 1) {
    s += __shfl_xor(s, off);
    q += __shfl_xor(q, off);
  }
  __shared__ float ss[4], sq[4];
  int wv = threadIdx.x >> 6;
  if ((threadIdx.x & 63) == 0) { ss[wv] = s; sq[wv] = q; }
  __syncthreads();
  if (threadIdx.x == 0) {
    float S = ss[0] + ss[1] + ss[2] + ss[3];
    float Q = sq[0] + sq[1] + sq[2] + sq[3];
    float mean = S * (1.f / HW_);
    float var = Q * (1.f / HW_) - mean * mean;
    float2 r;
    r.x = mean;
    r.y = rsqrtf(var + 1e-5f);
    (t == 0 ? cxs : (t == 1 ? c1s : s1s))[b * C_ + c] = r;
  }
}

// ------- pass 1: normalize + transpose (b,c,p) f32 -> (b,p,c) f16 ---------
__global__ __launch_bounds__(256) void k_prept(
    const float* __restrict__ src, const float2* __restrict__ st,
    f16* __restrict__ dst) {
  int pb = blockIdx.x * 64, cb = blockIdx.y * 64, b = blockIdx.z;
  __shared__ float t[64][65];
  int tj = threadIdx.x & 63, tr = threadIdx.x >> 6;
#pragma unroll 4
  for (int p = 0; p < 16; ++p) {
    int cl = p * 4 + tr;
    float2 mr = st[b * C_ + cb + cl];
    float v = src[(size_t)(b * C_ + cb + cl) * HW_ + pb + tj];
    t[cl][tj] = (v - mr.x) * mr.y;
  }
  __syncthreads();
#pragma unroll 4
  for (int p = 0; p < 16; ++p) {
    int pr = p * 4 + tr;
    dst[(size_t)(b * HW_ + pb + pr) * C_ + cb + tj] = (f16)t[tj][pr];
  }
}

// ---- pass 1b: Vcat[b][2c][k] = V, Vcat[b][2c+1][k] = V^2 (f16) -----------
__global__ __launch_bounds__(256) void k_prepv(const float* __restrict__ src,
                                               f16* __restrict__ vcat) {
  int gid = blockIdx.x * 256 + threadIdx.x;  // over B_*C_*HW_/8
  int bc = gid >> 9;
  int ko = (gid & 511) * 8;
  const float4* s = (const float4*)(src + (size_t)bc * HW_ + ko);
  float4 v0 = s[0], v1 = s[1];
  f16x8 v = {(f16)v0.x, (f16)v0.y, (f16)v0.z, (f16)v0.w,
             (f16)v1.x, (f16)v1.y, (f16)v1.z, (f16)v1.w};
  f16x8 v2 = v * v;
  int b = bc >> 9, c = bc & 511;
  f16* d = vcat + ((size_t)(b * 1024 + 2 * c)) * HW_ + ko;
  *(f16x8*)d = v;
  *(f16x8*)(d + HW_) = v2;
}

// ------------- pass 2: QK^T GEMM + exp-shifted score store ---------------
// 1D grid (npair*16), XCD-clustered: XCD x owns q-tiles [x*npair/8, +npair/8),
// kt-major progression -> Q-tiles stay resident in one L2.
// 128q x 256k tile, 4 waves 2x2 (wy: q-half, wx: 128-key half), BK=32.
__global__ __launch_bounds__(256, 2) void k_qk(
    const f16* __restrict__ Qt, const f16* __restrict__ Kt,
    f16* __restrict__ E, float2* __restrict__ mlpart,
    int qspan, int qt128, int npair) {
  int id = blockIdx.x, pair, kt;
  if ((npair & 7) == 0) {
    int xcd = id & 7, j = id >> 3, qrs = npair >> 3;
    pair = xcd * qrs + (j % qrs);
    kt = j / qrs;
  } else {
    pair = id >> 4;
    kt = id & 15;
  }
  int bz = pair / qt128, qt = pair - bz * qt128;

  const f16* Aq = Qt + ((size_t)(bz * qspan + qt * 128)) * C_;
  const f16* Bk = Kt + (size_t)bz * HW_ * C_ + (size_t)kt * 256 * C_;
  f16* Eb = E + ((size_t)(bz * qspan + qt * 128)) * HW_ + kt * 256;
  float2* mlb = mlpart + ((size_t)(bz * qspan + qt * 128)) * 16 + kt;

  __shared__ __align__(16) f16 As[128 * 32], Bs[256 * 32];
  __shared__ float sred[2][128];

  int t = threadIdx.x, wave = t >> 6, lane = t & 63, lq = lane & 15, quad = lane >> 4;
  int wy = wave >> 1, wx = wave & 1;
  int srow = t >> 2, scol = (t & 3) * 8;

  f32x4 acc[4][8];
#pragma unroll
  for (int mt = 0; mt < 4; ++mt)
#pragma unroll
    for (int nt = 0; nt < 8; ++nt) acc[mt][nt] = (f32x4){0, 0, 0, 0};

  for (int kc = 0; kc < 16; ++kc) {
    __syncthreads();
    g2l16(Aq + (size_t)srow * C_ + kc * 32 + scol, As + t * 8);
    g2l16(Aq + (size_t)(srow + 64) * C_ + kc * 32 + scol, As + 2048 + t * 8);
#pragma unroll
    for (int i = 0; i < 4; ++i)
      g2l16(Bk + (size_t)(srow + 64 * i) * C_ + kc * 32 + scol,
            Bs + i * 2048 + t * 8);
    __syncthreads();
    f16x8 af[4], bf[8];
#pragma unroll
    for (int mt = 0; mt < 4; ++mt)
      af[mt] = *(const f16x8*)(As + (wy * 64 + mt * 16 + lq) * 32 + quad * 8);
#pragma unroll
    for (int nt = 0; nt < 8; ++nt)
      bf[nt] = *(const f16x8*)(Bs + (wx * 128 + nt * 16 + lq) * 32 + quad * 8);
#pragma unroll
    for (int mt = 0; mt < 4; ++mt)
#pragma unroll
      for (int nt = 0; nt < 8; ++nt)
        acc[mt][nt] = mfma16(af[mt], bf[nt], acc[mt][nt]);
  }

  // ---- epilogue: tile row-max, E = exp(s - m_t), row-sum partials ----
#pragma unroll
  for (int mt = 0; mt < 4; ++mt)
#pragma unroll
    for (int r = 0; r < 4; ++r) {
      float v = -1e30f;
#pragma unroll
      for (int nt = 0; nt < 8; ++nt) v = fmaxf(v, acc[mt][nt][r]);
#pragma unroll
      for (int msk = 1; msk < 16; msk <<= 1) v = fmaxf(v, __shfl_xor(v, msk));
      if (lq == 0) sred[wx][wy * 64 + mt * 16 + quad * 4 + r] = v;
    }
  __syncthreads();
  float mrow[4][4];
#pragma unroll
  for (int mt = 0; mt < 4; ++mt)
#pragma unroll
    for (int r = 0; r < 4; ++r) {
      int rr = wy * 64 + mt * 16 + quad * 4 + r;
      mrow[mt][r] = fmaxf(sred[0][rr], sred[1][rr]);
    }
  __syncthreads();  // sred reads done before reuse

  float rsum[4][4];
#pragma unroll
  for (int mt = 0; mt < 4; ++mt)
#pragma unroll
    for (int r = 0; r < 4; ++r) rsum[mt][r] = 0.f;
#pragma unroll
  for (int mt = 0; mt < 4; ++mt)
#pragma unroll
    for (int nt = 0; nt < 8; ++nt) {
      f32x4 v = acc[mt][nt];
#pragma unroll
      for (int r = 0; r < 4; ++r) {
        float e = __expf(v[r] - mrow[mt][r]);
        rsum[mt][r] += e;
        Eb[(size_t)(wy * 64 + mt * 16 + quad * 4 + r) * HW_ +
           wx * 128 + nt * 16 + lq] = (f16)e;
      }
    }
#pragma unroll
  for (int mt = 0; mt < 4; ++mt)
#pragma unroll
    for (int r = 0; r < 4; ++r) {
      float v = rsum[mt][r];
#pragma unroll
      for (int msk = 1; msk < 16; msk <<= 1) v += __shfl_xor(v, msk);
      if (lq == 0) sred[wx][wy * 64 + mt * 16 + quad * 4 + r] = v;
    }
  __syncthreads();
  if (wx == 0 && lq == 0) {
#pragma unroll
    for (int mt = 0; mt < 4; ++mt)
#pragma unroll
      for (int r = 0; r < 4; ++r) {
        int rr = wy * 64 + mt * 16 + quad * 4 + r;
        mlb[(size_t)rr * 16] = make_float2(mrow[mt][r], sred[0][rr] + sred[1][rr]);
      }
  }
}

// ---- pass 3: exact softmax merge -> alpha[row][kt16] = exp(m_t-m)/l ------
__global__ __launch_bounds__(256) void k_red(const float2* __restrict__ mlpart,
                                             float* __restrict__ alpha) {
  int row = blockIdx.x * 256 + threadIdx.x;
  const float2* p = mlpart + (size_t)row * 16;
  float2 loc[16];
  float m = -1e30f;
#pragma unroll
  for (int i = 0; i < 16; ++i) {
    loc[i] = p[i];
    m = fmaxf(m, loc[i].x);
  }
  float l = 0.f;
#pragma unroll
  for (int i = 0; i < 16; ++i) l += loc[i].y * __expf(loc[i].x - m);
  float invl = 1.f / l;
#pragma unroll
  for (int i = 0; i < 16; ++i)
    alpha[(size_t)row * 16 + i] = __expf(loc[i].x - m) * invl;
}

// ------- pass 4: (E*alpha) x Vcat GEMM + fused variance/IN epilogue -------
// 1D grid, XCD-clustered: each XCD owns npairs/8 q-tiles x all 4 ct tiles
// so a P-tile is fetched into ONE L2 and hit by its 4 ct-blocks.
// 128q x 256ch2 tile, 4 waves 2x2 (wy: q-half, wx: 128-ch2 half).
__global__ __launch_bounds__(256, 2) void k_pv(
    const f16* __restrict__ P, const float* __restrict__ alphaG,
    const f16* __restrict__ Vcat, const float* __restrict__ cx,
    const float2* __restrict__ cxs, float* __restrict__ out,
    int qspan, int qbase, int qt128) {
  int npairs = (int)gridDim.x >> 2;
  int id = blockIdx.x, pair, ct;
  if ((npairs & 7) == 0) {
    int x = id & 7, j = id >> 3, ppx = npairs >> 3;
    pair = x * ppx + (j >> 2);
    ct = j & 3;
  } else {
    pair = id >> 2;
    ct = id & 3;
  }
  int bz = pair / qt128, qt = pair - bz * qt128;

  const f16* Ap = P + ((size_t)(bz * qspan + qt * 128)) * HW_;
  const f16* Bv = Vcat + ((size_t)(bz * 1024 + ct * 256)) * HW_;

  __shared__ __align__(16) f16 As[128 * 32], Bs[256 * 32];
  __shared__ float Al[128 * 17];  // alpha, stride 17 (coprime 32): conflict-free

  int t = threadIdx.x, wave = t >> 6, lane = t & 63, lq = lane & 15, quad = lane >> 4;
  int wy = wave >> 1, wx = wave & 1;
  int srow = t >> 2, scol = (t & 3) * 8;

  // stage alpha for this block's 128 rows x 16 kt (coalesced f32 loads)
  {
    const float* ag = alphaG + ((size_t)(bz * qspan + qt * 128)) * 16;
#pragma unroll
    for (int i = 0; i < 8; ++i) {
      int e = i * 256 + t;
      Al[(e >> 4) * 17 + (e & 15)] = ag[e];
    }
  }

  f32x4 acc[4][8];
#pragma unroll
  for (int mt = 0; mt < 4; ++mt)
#pragma unroll
    for (int nt = 0; nt < 8; ++nt) acc[mt][nt] = (f32x4){0, 0, 0, 0};

  for (int kc = 0; kc < 128; ++kc) {
    __syncthreads();  // prev iter LDS reads done (also covers alpha stage @kc=0)
    g2l16(Ap + (size_t)srow * HW_ + kc * 32 + scol, As + t * 8);
    g2l16(Ap + (size_t)(srow + 64) * HW_ + kc * 32 + scol, As + 2048 + t * 8);
#pragma unroll
    for (int i = 0; i < 4; ++i)
      g2l16(Bv + (size_t)(srow + 64 * i) * HW_ + kc * 32 + scol,
            Bs + i * 2048 + t * 8);
    __syncthreads();  // staging visible

    int ktl = kc >> 3;  // 256-key alpha tiles
    f16x8 af[4];
    f16x8 bf[8];
#pragma unroll
    for (int mt = 0; mt < 4; ++mt) {
      af[mt] = *(const f16x8*)(As + (wy * 64 + mt * 16 + lq) * 32 + quad * 8);
      f16 a = (f16)Al[(wy * 64 + mt * 16 + lq) * 17 + ktl];
      af[mt] = af[mt] * a;  // fold softmax alpha into A-fragment
    }
#pragma unroll
    for (int nt = 0; nt < 8; ++nt)
      bf[nt] = *(const f16x8*)(Bs + (wx * 128 + nt * 16 + lq) * 32 + quad * 8);
#pragma unroll
    for (int mt = 0; mt < 4; ++mt)
#pragma unroll
      for (int nt = 0; nt < 8; ++nt)
        acc[mt][nt] = mfma16(af[mt], bf[nt], acc[mt][nt]);
  }

  // epilogue: even lanes hold M (ch2=2c), odd hold M2; pair via shfl_xor(1)
  int ch2base = ct * 256 + wx * 128;
#pragma unroll
  for (int mt = 0; mt < 4; ++mt) {
    int q0 = qbase + qt * 128 + wy * 64 + mt * 16 + quad * 4;
#pragma unroll
    for (int nt = 0; nt < 8; ++nt) {
      f32x4 m1 = acc[mt][nt];
      f32x4 m2;
#pragma unroll
      for (int r = 0; r < 4; ++r) m2[r] = __shfl_xor(m1[r], 1);
      if (!(lane & 1)) {
        int c = (ch2base + nt * 16 + lq) >> 1;
        float2 st = cxs[bz * C_ + c];
        size_t base = ((size_t)bz * C_ + c) * HW_ + q0;
        float4 cv = *(const float4*)(cx + base);
        float4 o;
        o.x = sqrtf(fmaxf(m2[0] - m1[0] * m1[0], 1e-6f)) * ((cv.x - st.x) * st.y) + m1[0];
        o.y = sqrtf(fmaxf(m2[1] - m1[1] * m1[1], 1e-6f)) * ((cv.y - st.x) * st.y) + m1[1];
        o.z = sqrtf(fmaxf(m2[2] - m1[2] * m1[2], 1e-6f)) * ((cv.z - st.x) * st.y) + m1[2];
        o.w = sqrtf(fmaxf(m2[3] - m1[3] * m1[3], 1e-6f)) * ((cv.w - st.x) * st.y) + m1[3];
        *(float4*)(out + base) = o;
      }
    }
  }
}

// --------------------------------- host -----------------------------------
extern "C" void kernel_launch(void* const* d_in, const int* in_sizes, int n_in,
                              void* d_out, int out_size, void* d_ws,
                              size_t ws_size, hipStream_t stream) {
  const float* c_x = (const float*)d_in[0];
  const float* s_x = (const float*)d_in[1];
  const float* c1x = (const float*)d_in[2];
  const float* s1x = (const float*)d_in[3];
  float* out = (float*)d_out;

  char* ws = (char*)d_ws;
  size_t o = 0;
  f16* Qt = (f16*)(ws + o);  o += (size_t)B_ * HW_ * C_ * 2;        // 16 MiB
  f16* Kt = (f16*)(ws + o);  o += (size_t)B_ * HW_ * C_ * 2;        // 16 MiB
  f16* Vcat = (f16*)(ws + o); o += (size_t)B_ * HW_ * 1024 * 2;     // 32 MiB
  float2* cxs = (float2*)(ws + o); o += B_ * C_ * sizeof(float2);
  float2* c1s = (float2*)(ws + o); o += B_ * C_ * sizeof(float2);
  float2* s1s = (float2*)(ws + o); o += B_ * C_ * sizeof(float2);
  size_t fixed = (o + 255) & ~(size_t)255;

  // score-region tiers: rows = nb*qspan; bytes/row = E + mlpart + alpha(f32)
  const size_t per_row = (size_t)HW_ * 2 + 16 * 8 + 16 * 4;
  struct Cfg { int nb, qs; };
  const Cfg cfgs[5] = {{4, 4096}, {1, 4096}, {1, 2048}, {1, 1024}, {1, 512}};
  Cfg cfg = cfgs[4];
  for (int i = 0; i < 5; ++i) {
    size_t rows = (size_t)cfgs[i].nb * cfgs[i].qs;
    if (fixed + rows * per_row <= ws_size) { cfg = cfgs[i]; break; }
  }
  const int nb = cfg.nb, qspan = cfg.qs, qt128 = qspan / 128;
  const int npair = nb * qt128;
  const size_t rows = (size_t)nb * qspan;
  f16* E = (f16*)(ws + fixed);
  float2* mlpart = (float2*)(ws + fixed + rows * HW_ * 2);
  float* alpha = (float*)(ws + fixed + rows * HW_ * 2 + rows * 16 * 8);

  k_stats<<<dim3(C_, B_, 3), 256, 0, stream>>>(c_x, c1x, s1x, cxs, c1s, s1s);
  k_prept<<<dim3(HW_ / 64, C_ / 64, B_), 256, 0, stream>>>(c1x, c1s, Qt);
  k_prept<<<dim3(HW_ / 64, C_ / 64, B_), 256, 0, stream>>>(s1x, s1s, Kt);
  k_prepv<<<dim3(B_ * C_ * HW_ / 8 / 256), 256, 0, stream>>>(s_x, Vcat);

  for (int b0 = 0; b0 < B_; b0 += nb) {
    for (int qb = 0; qb < HW_; qb += qspan) {
      const f16* Qtp = Qt + ((size_t)b0 * HW_ + qb) * C_;
      const f16* Ktp = Kt + (size_t)b0 * HW_ * C_;
      const f16* Vcp = Vcat + (size_t)b0 * 1024 * HW_;
      const float* cxp = c_x + (size_t)b0 * C_ * HW_;
      const float2* cxsp = cxs + b0 * C_;
      float* outp = out + (size_t)b0 * C_ * HW_;

      k_qk<<<dim3((unsigned)(npair * 16)), 256, 0, stream>>>(
          Qtp, Ktp, E, mlpart, qspan, qt128, npair);
      k_red<<<dim3((unsigned)(rows / 256)), 256, 0, stream>>>(mlpart, alpha);
      k_pv<<<dim3((unsigned)(npair * 4)), 256, 0, stream>>>(
          E, alpha, Vcp, cxp, cxsp, outp, qspan, qb, qt128);
    }
  }
}

// Round 6
// 423.888 us; speedup vs baseline: 2.5028x; 1.0989x over previous
//
#include <hip/hip_runtime.h>
#include <cmath>

// AdaAttnNoConv: b=4, C=512, hw=4096 (fp32 in/out).
// Round 6:
//  - k_pv: V^2 computed in-register from the V B-fragment (Vcat dropped) ->
//    half the B staging bytes/drain depth, separate M/M2 accumulators,
//    all-lane epilogue (no shfl pairing). V stored plain f16 [b][c][k].
//  - k_qk: epilogue E-store via LDS transpose -> coalesced 16B stores
//    (was 128 scalar 2B stores/lane).
//   k_qk : S-tile GEMM, epilogue stores E = exp(s - m_tile) f16 + (m_t, l_t)
//   k_red: exact softmax merge -> alpha[row][kt16] = exp(m_t - m)/l  (f32)
//   k_pv : (E*alpha) x V GEMM, M=A.V, M2=A.V^2 (in-reg square),
//          fused sqrt(clip(M2-M^2))*IN(c_x)+M epilogue. XCD-clustered.

#define B_  4
#define C_  512
#define HW_ 4096

typedef _Float16 f16;
typedef _Float16 f16x8 __attribute__((ext_vector_type(8)));
typedef float    f32x4 __attribute__((ext_vector_type(4)));

// Verified gfx950 fragment layouts (learn_hip m89/m91, rounds 1-5 passed):
//  A[m][k]: m = lane&15, k = quad*8 + j
//  B[k][n]: n = lane&15, k = quad*8 + j
//  C/D[m][n]: n = lane&15, m = quad*4 + reg
__device__ __forceinline__ f32x4 mfma16(f16x8 a, f16x8 b, f32x4 c) {
  return __builtin_amdgcn_mfma_f32_16x16x32_f16(a, b, c, 0, 0, 0);
}
__device__ __forceinline__ void g2l16(const f16* g, f16* l) {
  __builtin_amdgcn_global_load_lds(
      (const __attribute__((address_space(1))) void*)g,
      (__attribute__((address_space(3))) void*)l, 16, 0, 0);
}

// ---------------- pass 0: instance-norm stats (mean, rstd) ----------------
__global__ __launch_bounds__(256) void k_stats(
    const float* __restrict__ cx, const float* __restrict__ c1,
    const float* __restrict__ s1,
    float2* __restrict__ cxs, float2* __restrict__ c1s, float2* __restrict__ s1s) {
  int c = blockIdx.x, b = blockIdx.y, t = blockIdx.z;
  const float* src = (t == 0 ? cx : (t == 1 ? c1 : s1)) + (size_t)(b * C_ + c) * HW_;
  float s = 0.f, q = 0.f;
  const float4* src4 = (const float4*)src;
  for (int i = threadIdx.x; i < HW_ / 4; i += 256) {
    float4 v = src4[i];
    s += v.x + v.y + v.z + v.w;
    q += v.x * v.x + v.y * v.y + v.z * v.z + v.w * v.w;
  }
#pragma unroll
  for (int off = 1; off < 64; off <<= 1) {
    s += __shfl_xor(s, off);
    q += __shfl_xor(q, off);
  }
  __shared__ float ss[4], sq[4];
  int wv = threadIdx.x >> 6;
  if ((threadIdx.x & 63) == 0) { ss[wv] = s; sq[wv] = q; }
  __syncthreads();
  if (threadIdx.x == 0) {
    float S = ss[0] + ss[1] + ss[2] + ss[3];
    float Q = sq[0] + sq[1] + sq[2] + sq[3];
    float mean = S * (1.f / HW_);
    float var = Q * (1.f / HW_) - mean * mean;
    float2 r;
    r.x = mean;
    r.y = rsqrtf(var + 1e-5f);
    (t == 0 ? cxs : (t == 1 ? c1s : s1s))[b * C_ + c] = r;
  }
}

// ------- pass 1: normalize + transpose (b,c,p) f32 -> (b,p,c) f16 ---------
__global__ __launch_bounds__(256) void k_prept(
    const float* __restrict__ src, const float2* __restrict__ st,
    f16* __restrict__ dst) {
  int pb = blockIdx.x * 64, cb = blockIdx.y * 64, b = blockIdx.z;
  __shared__ float t[64][65];
  int tj = threadIdx.x & 63, tr = threadIdx.x >> 6;
#pragma unroll 4
  for (int p = 0; p < 16; ++p) {
    int cl = p * 4 + tr;
    float2 mr = st[b * C_ + cb + cl];
    float v = src[(size_t)(b * C_ + cb + cl) * HW_ + pb + tj];
    t[cl][tj] = (v - mr.x) * mr.y;
  }
  __syncthreads();
#pragma unroll 4
  for (int p = 0; p < 16; ++p) {
    int pr = p * 4 + tr;
    dst[(size_t)(b * HW_ + pb + pr) * C_ + cb + tj] = (f16)t[tj][pr];
  }
}

// ---------------- pass 1b: V = s_x -> f16 (same [b][c][k] layout) ---------
__global__ __launch_bounds__(256) void k_prepv(const float* __restrict__ src,
                                               f16* __restrict__ dst) {
  int gid = blockIdx.x * 256 + threadIdx.x;  // over B_*C_*HW_/8
  const float4* s = (const float4*)src + (size_t)gid * 2;
  float4 v0 = s[0], v1 = s[1];
  f16x8 v = {(f16)v0.x, (f16)v0.y, (f16)v0.z, (f16)v0.w,
             (f16)v1.x, (f16)v1.y, (f16)v1.z, (f16)v1.w};
  *(f16x8*)(dst + (size_t)gid * 8) = v;
}

// ------------- pass 2: QK^T GEMM + exp-shifted score store ---------------
// 1D grid (npair*16), XCD-clustered: XCD x owns q-tiles [x*npair/8, +npair/8),
// kt-major progression -> Q-tiles stay resident in one L2.
// 128q x 256k tile, 4 waves 2x2 (wy: q-half, wx: 128-key half), BK=32.
__global__ __launch_bounds__(256, 2) void k_qk(
    const f16* __restrict__ Qt, const f16* __restrict__ Kt,
    f16* __restrict__ E, float2* __restrict__ mlpart,
    int qspan, int qt128, int npair) {
  int id = blockIdx.x, pair, kt;
  if ((npair & 7) == 0) {
    int xcd = id & 7, j = id >> 3, qrs = npair >> 3;
    pair = xcd * qrs + (j % qrs);
    kt = j / qrs;
  } else {
    pair = id >> 4;
    kt = id & 15;
  }
  int bz = pair / qt128, qt = pair - bz * qt128;

  const f16* Aq = Qt + ((size_t)(bz * qspan + qt * 128)) * C_;
  const f16* Bk = Kt + (size_t)bz * HW_ * C_ + (size_t)kt * 256 * C_;
  f16* Eb = E + ((size_t)(bz * qspan + qt * 128)) * HW_ + kt * 256;
  float2* mlb = mlpart + ((size_t)(bz * qspan + qt * 128)) * 16 + kt;

  // As/Bs for the K-loop; ebuf (32 rows x 272-stride) reuses the same LDS
  // for the epilogue transpose (stride 272 f16 = 136 dwords == 8 mod 32 ->
  // quads land on disjoint bank groups).
  __shared__ __align__(16) union ShQK {
    struct { f16 As[128 * 32]; f16 Bs[256 * 32]; } s;
    f16 ebuf[32 * 272];
  } sh;
  __shared__ float sred[2][128];
  f16* As = sh.s.As;
  f16* Bs = sh.s.Bs;

  int t = threadIdx.x, wave = t >> 6, lane = t & 63, lq = lane & 15, quad = lane >> 4;
  int wy = wave >> 1, wx = wave & 1;
  int srow = t >> 2, scol = (t & 3) * 8;

  f32x4 acc[4][8];
#pragma unroll
  for (int mt = 0; mt < 4; ++mt)
#pragma unroll
    for (int nt = 0; nt < 8; ++nt) acc[mt][nt] = (f32x4){0, 0, 0, 0};

  for (int kc = 0; kc < 16; ++kc) {
    __syncthreads();
    g2l16(Aq + (size_t)srow * C_ + kc * 32 + scol, As + t * 8);
    g2l16(Aq + (size_t)(srow + 64) * C_ + kc * 32 + scol, As + 2048 + t * 8);
#pragma unroll
    for (int i = 0; i < 4; ++i)
      g2l16(Bk + (size_t)(srow + 64 * i) * C_ + kc * 32 + scol,
            Bs + i * 2048 + t * 8);
    __syncthreads();
    f16x8 af[4], bf[8];
#pragma unroll
    for (int mt = 0; mt < 4; ++mt)
      af[mt] = *(const f16x8*)(As + (wy * 64 + mt * 16 + lq) * 32 + quad * 8);
#pragma unroll
    for (int nt = 0; nt < 8; ++nt)
      bf[nt] = *(const f16x8*)(Bs + (wx * 128 + nt * 16 + lq) * 32 + quad * 8);
#pragma unroll
    for (int mt = 0; mt < 4; ++mt)
#pragma unroll
      for (int nt = 0; nt < 8; ++nt)
        acc[mt][nt] = mfma16(af[mt], bf[nt], acc[mt][nt]);
  }

  // ---- tile row max (merge wx halves through sred) ----
#pragma unroll
  for (int mt = 0; mt < 4; ++mt)
#pragma unroll
    for (int r = 0; r < 4; ++r) {
      float v = -1e30f;
#pragma unroll
      for (int nt = 0; nt < 8; ++nt) v = fmaxf(v, acc[mt][nt][r]);
#pragma unroll
      for (int msk = 1; msk < 16; msk <<= 1) v = fmaxf(v, __shfl_xor(v, msk));
      if (lq == 0) sred[wx][wy * 64 + mt * 16 + quad * 4 + r] = v;
    }
  __syncthreads();
  float mrow[4][4];
#pragma unroll
  for (int mt = 0; mt < 4; ++mt)
#pragma unroll
    for (int r = 0; r < 4; ++r) {
      int rr = wy * 64 + mt * 16 + quad * 4 + r;
      mrow[mt][r] = fmaxf(sred[0][rr], sred[1][rr]);
    }

  // ---- E = exp(s - m_t): LDS transpose -> coalesced 16B stores ----
  float rsum[4][4];
#pragma unroll
  for (int mt = 0; mt < 4; ++mt)
#pragma unroll
    for (int r = 0; r < 4; ++r) rsum[mt][r] = 0.f;

#pragma unroll
  for (int mt = 0; mt < 4; ++mt) {
    __syncthreads();  // prev phase's ebuf reads done (mt=0: K-loop/sred done)
#pragma unroll
    for (int nt = 0; nt < 8; ++nt) {
      f32x4 v = acc[mt][nt];
#pragma unroll
      for (int r = 0; r < 4; ++r) {
        float e = __expf(v[r] - mrow[mt][r]);
        rsum[mt][r] += e;
        sh.ebuf[(wy * 16 + quad * 4 + r) * 272 + wx * 128 + nt * 16 + lq] = (f16)e;
      }
    }
    __syncthreads();  // ebuf visible
#pragma unroll
    for (int i = 0; i < 4; ++i) {
      int idx = i * 256 + t;
      int rl = idx >> 5, cs = (idx & 31) * 8;
      f16x8 v8 = *(const f16x8*)(sh.ebuf + rl * 272 + cs);
      int grow = (rl >> 4) * 64 + mt * 16 + (rl & 15);
      *(f16x8*)(Eb + (size_t)grow * HW_ + cs) = v8;
    }
  }

  // ---- row-sum partials -> mlpart ----
#pragma unroll
  for (int mt = 0; mt < 4; ++mt)
#pragma unroll
    for (int r = 0; r < 4; ++r) {
      float v = rsum[mt][r];
#pragma unroll
      for (int msk = 1; msk < 16; msk <<= 1) v += __shfl_xor(v, msk);
      if (lq == 0) sred[wx][wy * 64 + mt * 16 + quad * 4 + r] = v;
    }
  __syncthreads();
  if (wx == 0 && lq == 0) {
#pragma unroll
    for (int mt = 0; mt < 4; ++mt)
#pragma unroll
      for (int r = 0; r < 4; ++r) {
        int rr = wy * 64 + mt * 16 + quad * 4 + r;
        mlb[(size_t)rr * 16] = make_float2(mrow[mt][r], sred[0][rr] + sred[1][rr]);
      }
  }
}

// ---- pass 3: exact softmax merge -> alpha[row][kt16] = exp(m_t-m)/l ------
__global__ __launch_bounds__(256) void k_red(const float2* __restrict__ mlpart,
                                             float* __restrict__ alpha) {
  int row = blockIdx.x * 256 + threadIdx.x;
  const float2* p = mlpart + (size_t)row * 16;
  float2 loc[16];
  float m = -1e30f;
#pragma unroll
  for (int i = 0; i < 16; ++i) {
    loc[i] = p[i];
    m = fmaxf(m, loc[i].x);
  }
  float l = 0.f;
#pragma unroll
  for (int i = 0; i < 16; ++i) l += loc[i].y * __expf(loc[i].x - m);
  float invl = 1.f / l;
#pragma unroll
  for (int i = 0; i < 16; ++i)
    alpha[(size_t)row * 16 + i] = __expf(loc[i].x - m) * invl;
}

// ------ pass 4: (E*alpha) x V GEMM, V^2 in-register + fused epilogue ------
// 1D grid, XCD-clustered: each XCD owns npairs/8 q-tiles x all 4 ct tiles
// so a P-tile is fetched into ONE L2 and hit by its 4 ct-blocks.
// 128q x 128ch tile, two accumulator planes (M from V, M2 from V*V in-reg).
// 4 waves 2x2 (wy: q-half, wx: 64-ch half).
__global__ __launch_bounds__(256, 2) void k_pv(
    const f16* __restrict__ P, const float* __restrict__ alphaG,
    const f16* __restrict__ V, const float* __restrict__ cx,
    const float2* __restrict__ cxs, float* __restrict__ out,
    int qspan, int qbase, int qt128) {
  int npairs = (int)gridDim.x >> 2;
  int id = blockIdx.x, pair, ct;
  if ((npairs & 7) == 0) {
    int x = id & 7, j = id >> 3, ppx = npairs >> 3;
    pair = x * ppx + (j >> 2);
    ct = j & 3;
  } else {
    pair = id >> 2;
    ct = id & 3;
  }
  int bz = pair / qt128, qt = pair - bz * qt128;

  const f16* Ap = P + ((size_t)(bz * qspan + qt * 128)) * HW_;
  const f16* Bv = V + ((size_t)(bz * C_ + ct * 128)) * HW_;

  __shared__ __align__(16) f16 As[128 * 32], Bs[128 * 32];
  __shared__ float Al[128 * 17];  // alpha, stride 17 (coprime 32): conflict-free

  int t = threadIdx.x, wave = t >> 6, lane = t & 63, lq = lane & 15, quad = lane >> 4;
  int wy = wave >> 1, wx = wave & 1;
  int srow = t >> 2, scol = (t & 3) * 8;

  // stage alpha for this block's 128 rows x 16 kt (coalesced f32 loads)
  {
    const float* ag = alphaG + ((size_t)(bz * qspan + qt * 128)) * 16;
#pragma unroll
    for (int i = 0; i < 8; ++i) {
      int e = i * 256 + t;
      Al[(e >> 4) * 17 + (e & 15)] = ag[e];
    }
  }

  f32x4 accM[4][4], accM2[4][4];
#pragma unroll
  for (int mt = 0; mt < 4; ++mt)
#pragma unroll
    for (int nt = 0; nt < 4; ++nt) {
      accM[mt][nt] = (f32x4){0, 0, 0, 0};
      accM2[mt][nt] = (f32x4){0, 0, 0, 0};
    }

  for (int kc = 0; kc < 128; ++kc) {
    __syncthreads();  // prev iter LDS reads done (also covers alpha stage @kc=0)
    g2l16(Ap + (size_t)srow * HW_ + kc * 32 + scol, As + t * 8);
    g2l16(Ap + (size_t)(srow + 64) * HW_ + kc * 32 + scol, As + 2048 + t * 8);
    g2l16(Bv + (size_t)srow * HW_ + kc * 32 + scol, Bs + t * 8);
    g2l16(Bv + (size_t)(srow + 64) * HW_ + kc * 32 + scol, Bs + 2048 + t * 8);
    __syncthreads();  // staging visible

    int ktl = kc >> 3;  // 256-key alpha tiles
    f16x8 af[4], bf[4], bf2[4];
#pragma unroll
    for (int mt = 0; mt < 4; ++mt) {
      af[mt] = *(const f16x8*)(As + (wy * 64 + mt * 16 + lq) * 32 + quad * 8);
      f16 a = (f16)Al[(wy * 64 + mt * 16 + lq) * 17 + ktl];
      af[mt] = af[mt] * a;  // fold softmax alpha into A-fragment
    }
#pragma unroll
    for (int nt = 0; nt < 4; ++nt) {
      bf[nt] = *(const f16x8*)(Bs + (wx * 64 + nt * 16 + lq) * 32 + quad * 8);
      bf2[nt] = bf[nt] * bf[nt];  // V^2 in-register (bit-identical to prep)
    }
#pragma unroll
    for (int mt = 0; mt < 4; ++mt)
#pragma unroll
      for (int nt = 0; nt < 4; ++nt) {
        accM[mt][nt] = mfma16(af[mt], bf[nt], accM[mt][nt]);
        accM2[mt][nt] = mfma16(af[mt], bf2[nt], accM2[mt][nt]);
      }
  }

  // epilogue: all lanes active; lane lq = channel, rows q0..q0+3
  int chbase = ct * 128 + wx * 64;
#pragma unroll
  for (int mt = 0; mt < 4; ++mt) {
    int q0 = qbase + qt * 128 + wy * 64 + mt * 16 + quad * 4;
#pragma unroll
    for (int nt = 0; nt < 4; ++nt) {
      int c = chbase + nt * 16 + lq;
      float2 st = cxs[bz * C_ + c];
      size_t base = ((size_t)bz * C_ + c) * HW_ + q0;
      float4 cv = *(const float4*)(cx + base);
      f32x4 m1 = accM[mt][nt], m2 = accM2[mt][nt];
      float4 o;
      o.x = sqrtf(fmaxf(m2[0] - m1[0] * m1[0], 1e-6f)) * ((cv.x - st.x) * st.y) + m1[0];
      o.y = sqrtf(fmaxf(m2[1] - m1[1] * m1[1], 1e-6f)) * ((cv.y - st.x) * st.y) + m1[1];
      o.z = sqrtf(fmaxf(m2[2] - m1[2] * m1[2], 1e-6f)) * ((cv.z - st.x) * st.y) + m1[2];
      o.w = sqrtf(fmaxf(m2[3] - m1[3] * m1[3], 1e-6f)) * ((cv.w - st.x) * st.y) + m1[3];
      *(float4*)(out + base) = o;
    }
  }
}

// --------------------------------- host -----------------------------------
extern "C" void kernel_launch(void* const* d_in, const int* in_sizes, int n_in,
                              void* d_out, int out_size, void* d_ws,
                              size_t ws_size, hipStream_t stream) {
  const float* c_x = (const float*)d_in[0];
  const float* s_x = (const float*)d_in[1];
  const float* c1x = (const float*)d_in[2];
  const float* s1x = (const float*)d_in[3];
  float* out = (float*)d_out;

  char* ws = (char*)d_ws;
  size_t o = 0;
  f16* Qt = (f16*)(ws + o);  o += (size_t)B_ * HW_ * C_ * 2;        // 16 MiB
  f16* Kt = (f16*)(ws + o);  o += (size_t)B_ * HW_ * C_ * 2;        // 16 MiB
  f16* Vh = (f16*)(ws + o);  o += (size_t)B_ * HW_ * C_ * 2;        // 16 MiB
  float2* cxs = (float2*)(ws + o); o += B_ * C_ * sizeof(float2);
  float2* c1s = (float2*)(ws + o); o += B_ * C_ * sizeof(float2);
  float2* s1s = (float2*)(ws + o); o += B_ * C_ * sizeof(float2);
  size_t fixed = (o + 255) & ~(size_t)255;

  // score-region tiers: rows = nb*qspan; bytes/row = E + mlpart + alpha(f32)
  const size_t per_row = (size_t)HW_ * 2 + 16 * 8 + 16 * 4;
  struct Cfg { int nb, qs; };
  const Cfg cfgs[5] = {{4, 4096}, {1, 4096}, {1, 2048}, {1, 1024}, {1, 512}};
  Cfg cfg = cfgs[4];
  for (int i = 0; i < 5; ++i) {
    size_t rows = (size_t)cfgs[i].nb * cfgs[i].qs;
    if (fixed + rows * per_row <= ws_size) { cfg = cfgs[i]; break; }
  }
  const int nb = cfg.nb, qspan = cfg.qs, qt128 = qspan / 128;
  const int npair = nb * qt128;
  const size_t rows = (size_t)nb * qspan;
  f16* E = (f16*)(ws + fixed);
  float2* mlpart = (float2*)(ws + fixed + rows * HW_ * 2);
  float* alpha = (float*)(ws + fixed + rows * HW_ * 2 + rows * 16 * 8);

  k_stats<<<dim3(C_, B_, 3), 256, 0, stream>>>(c_x, c1x, s1x, cxs, c1s, s1s);
  k_prept<<<dim3(HW_ / 64, C_ / 64, B_), 256, 0, stream>>>(c1x, c1s, Qt);
  k_prept<<<dim3(HW_ / 64, C_ / 64, B_), 256, 0, stream>>>(s1x, s1s, Kt);
  k_prepv<<<dim3(B_ * C_ * HW_ / 8 / 256), 256, 0, stream>>>(s_x, Vh);

  for (int b0 = 0; b0 < B_; b0 += nb) {
    for (int qb = 0; qb < HW_; qb += qspan) {
      const f16* Qtp = Qt + ((size_t)b0 * HW_ + qb) * C_;
      const f16* Ktp = Kt + (size_t)b0 * HW_ * C_;
      const f16* Vp = Vh + (size_t)b0 * C_ * HW_;
      const float* cxp = c_x + (size_t)b0 * C_ * HW_;
      const float2* cxsp = cxs + b0 * C_;
      float* outp = out + (size_t)b0 * C_ * HW_;

      k_qk<<<dim3((unsigned)(npair * 16)), 256, 0, stream>>>(
          Qtp, Ktp, E, mlpart, qspan, qt128, npair);
      k_red<<<dim3((unsigned)(rows / 256)), 256, 0, stream>>>(mlpart, alpha);
      k_pv<<<dim3((unsigned)(npair * 4)), 256, 0, stream>>>(
          E, alpha, Vp, cxp, cxsp, outp, qspan, qb, qt128);
    }
  }
}